// Round 8
// baseline (312.155 us; speedup 1.0000x reference)
//
#include <hip/hip_runtime.h>
#include <hip/hip_bf16.h>
#include <math.h>

#define BB 2
#define SS 1024
#define HH 2048
#define NHD 16
#define NOPE 128
#define ROPED 64
#define VDIM 128
#define QKD 192
#define QLR 1536
#define KVLR 512
#define EPSF 1e-5f
#define NCOMB 2176   // QLR + 576 kv + 64 pad

typedef __bf16 bf16x8 __attribute__((ext_vector_type(8)));
typedef float  f32x4  __attribute__((ext_vector_type(4)));

__device__ __forceinline__ void gload_lds16(const __bf16* g, __bf16* l) {
    __builtin_amdgcn_global_load_lds(
        (const __attribute__((address_space(1))) void*)g,
        (__attribute__((address_space(3))) void*)l, 16, 0, 0);
}

// XCD-chunked bijective tile swizzle (T1, validated R6: FETCH drop + ~8 µs).
__device__ __forceinline__ void swz2d(int nx, int ny, int& bx, int& by) {
    int T = nx * ny;
    int lin = blockIdx.x + nx * blockIdx.y;
    if ((T & 7) == 0) {
        int q = T >> 3;
        lin = (lin & 7) * q + (lin >> 3);
    }
    bx = lin % nx;
    by = lin / nx;
}

// ---------------------------------------------------------------------------
// Double-buffered 2-barrier core (R1 schedule, proven): for dense big-K GEMMs.
// XOR swizzle (both-sides involution, verified): BK=64 chunk^=row&7.
// ---------------------------------------------------------------------------
template<int BK>
__device__ __forceinline__ void gemm_core_dbuf(
    const __bf16* __restrict__ Ab, const __bf16* __restrict__ Bb,
    int lda, int ldb, int m0, int n0, int K, __bf16* lds, f32x4 acc[4][4])
{
    constexpr int CH    = BK / 8;
    constexpr int LPT   = CH / 2;
    constexpr int BUFE  = 256 * BK;
    constexpr int BOFF  = 128 * BK;
    constexpr int RSTEP = 2048 / BK;
    const int tid = threadIdx.x;
    const int w = tid >> 6, lane = tid & 63, quad = lane >> 4, ln = lane & 15;
    const int wm = (w >> 1) * 64, wn = (w & 1) * 64;
    const int nt = K / BK;

    const int sr  = tid / CH;
    const int spc = tid % CH;
    const int sc  = (BK == 64) ? (spc ^ (sr & 7)) : (spc ^ ((sr >> 1) & 3));
    const __bf16* gA = Ab + (size_t)(m0 + sr) * lda + sc * 8;
    const __bf16* gB = Bb + (size_t)(n0 + sr) * ldb + sc * 8;

    const int swm = (BK == 64) ? ((wm + ln) & 7) : (((wm + ln) >> 1) & 3);
    const int swn = (BK == 64) ? ((wn + ln) & 7) : (((wn + ln) >> 1) & 3);

    auto stage = [&](int buf, int kk) {
        __bf16* la = lds + buf * BUFE + w * 512;
        __bf16* lb = la + BOFF;
        const __bf16* ga = gA + kk;
        const __bf16* gb = gB + kk;
#pragma unroll
        for (int i = 0; i < LPT; ++i) {
            gload_lds16(ga + (size_t)(i * RSTEP) * lda, la + i * 2048);
            gload_lds16(gb + (size_t)(i * RSTEP) * ldb, lb + i * 2048);
        }
    };
    auto wait_stage = [&]() {
        if constexpr (BK == 64) asm volatile("s_waitcnt vmcnt(8)" ::: "memory");
        else                    asm volatile("s_waitcnt vmcnt(4)" ::: "memory");
    };

    stage(0, 0);
    stage(1, BK);
    wait_stage();
    __builtin_amdgcn_s_barrier();
    __builtin_amdgcn_sched_barrier(0);

    for (int t = 0; t < nt; ++t) {
        const int cur = t & 1;
        const __bf16* bufA = lds + cur * BUFE;
        const __bf16* bufB = bufA + BOFF;
        bf16x8 af[BK / 32][4], bv[BK / 32][4];
#pragma unroll
        for (int ks = 0; ks < BK / 32; ++ks)
#pragma unroll
            for (int i = 0; i < 4; ++i) {
                af[ks][i] = *(const bf16x8*)
                    &bufA[(wm + ln) * BK + i * 16 * BK + (((ks * 4 + quad) ^ swm) << 3)];
                bv[ks][i] = *(const bf16x8*)
                    &bufB[(wn + ln) * BK + i * 16 * BK + (((ks * 4 + quad) ^ swn) << 3)];
            }
        __builtin_amdgcn_s_setprio(1);
#pragma unroll
        for (int ks = 0; ks < BK / 32; ++ks)
#pragma unroll
            for (int mi = 0; mi < 4; ++mi)
#pragma unroll
                for (int ni = 0; ni < 4; ++ni)
                    acc[mi][ni] = __builtin_amdgcn_mfma_f32_16x16x32_bf16(
                        af[ks][mi], bv[ks][ni], acc[mi][ni], 0, 0, 0);
        __builtin_amdgcn_s_setprio(0);
        if (t + 1 < nt) {
            __builtin_amdgcn_sched_barrier(0);
            asm volatile("" ::: "memory");
            __builtin_amdgcn_s_barrier();          // (a) reads of buf[cur] done
            asm volatile("" ::: "memory");
            if (t + 2 < nt) {
                stage(cur, (t + 2) * BK);
                wait_stage();
            } else {
                asm volatile("s_waitcnt vmcnt(0)" ::: "memory");
            }
            __builtin_amdgcn_s_barrier();          // (b) publish t+1
            __builtin_amdgcn_sched_barrier(0);
        }
    }
}

// ---------------------------------------------------------------------------
// Triple-buffered 1-barrier core (BK=32: 48 KB LDS -> 3 blocks/CU).
// R8: compiler-scheduled ds_read->MFMA. The old explicit lgkmcnt(0)+
// sched_barrier pin forced all 8 ds_read_b128 (~120cy) to retire before ANY
// MFMA (rule #18 applies to inline-asm ds_reads only; these are plain loads
// with register deps — compiler emits fine-grained lgkmcnt, m97 evidence).
// stage() is issued FIRST (longest-latency ops). The sched_barrier(0)
// fences around s_barrier still pin cross-iteration ordering: ds_reads of
// tile t+1 cannot hoist above the publish barrier. Counted-vmcnt schedule
// unchanged (race screen R3/R4 intact).
// ---------------------------------------------------------------------------
template<int BK>
__device__ __forceinline__ void gemm_core_tri(
    const __bf16* __restrict__ Ab, const __bf16* __restrict__ Bb,
    int lda, int ldb, int m0, int n0, int K, __bf16* lds, f32x4 acc[4][4])
{
    constexpr int CH    = BK / 8;
    constexpr int LPT   = CH / 2;
    constexpr int BUFE  = 256 * BK;
    constexpr int BOFF  = 128 * BK;
    constexpr int RSTEP = 2048 / BK;
    const int tid = threadIdx.x;
    const int w = tid >> 6, lane = tid & 63, quad = lane >> 4, ln = lane & 15;
    const int wm = (w >> 1) * 64, wn = (w & 1) * 64;
    const int nt = K / BK;

    const int sr  = tid / CH;
    const int spc = tid % CH;
    const int sc  = (BK == 64) ? (spc ^ (sr & 7)) : (spc ^ ((sr >> 1) & 3));
    const __bf16* gA = Ab + (size_t)(m0 + sr) * lda + sc * 8;
    const __bf16* gB = Bb + (size_t)(n0 + sr) * ldb + sc * 8;

    const int swm = (BK == 64) ? ((wm + ln) & 7) : (((wm + ln) >> 1) & 3);
    const int swn = (BK == 64) ? ((wn + ln) & 7) : (((wn + ln) >> 1) & 3);

    auto stage = [&](__bf16* base, int kk) {
        __bf16* la = base + w * 512;
        __bf16* lb = la + BOFF;
        const __bf16* ga = gA + kk;
        const __bf16* gb = gB + kk;
#pragma unroll
        for (int i = 0; i < LPT; ++i) {
            gload_lds16(ga + (size_t)(i * RSTEP) * lda, la + i * 2048);
            gload_lds16(gb + (size_t)(i * RSTEP) * ldb, lb + i * 2048);
        }
    };

    __bf16* p0 = lds;               // tile t
    __bf16* p1 = lds + BUFE;        // tile t+1
    __bf16* p2 = lds + 2 * BUFE;    // stage target (tile t+2)

    stage(p0, 0);
    stage(p1, BK);
    if constexpr (BK == 64) asm volatile("s_waitcnt vmcnt(8)" ::: "memory");
    else                    asm volatile("s_waitcnt vmcnt(4)" ::: "memory");
    __builtin_amdgcn_s_barrier();
    __builtin_amdgcn_sched_barrier(0);

    for (int t = 0; t < nt; ++t) {
        if (t + 2 < nt) stage(p2, (t + 2) * BK);   // issue global loads first
        bf16x8 af[BK / 32][4], bv[BK / 32][4];
#pragma unroll
        for (int ks = 0; ks < BK / 32; ++ks)
#pragma unroll
            for (int i = 0; i < 4; ++i) {
                af[ks][i] = *(const bf16x8*)
                    &p0[(wm + ln) * BK + i * 16 * BK + (((ks * 4 + quad) ^ swm) << 3)];
                bv[ks][i] = *(const bf16x8*)
                    &p0[BOFF + (wn + ln) * BK + i * 16 * BK + (((ks * 4 + quad) ^ swn) << 3)];
            }
        __builtin_amdgcn_s_setprio(1);
#pragma unroll
        for (int ks = 0; ks < BK / 32; ++ks)
#pragma unroll
            for (int mi = 0; mi < 4; ++mi)
#pragma unroll
                for (int ni = 0; ni < 4; ++ni)
                    acc[mi][ni] = __builtin_amdgcn_mfma_f32_16x16x32_bf16(
                        af[ks][mi], bv[ks][ni], acc[mi][ni], 0, 0, 0);
        __builtin_amdgcn_s_setprio(0);
        if (t + 1 < nt) {
            __builtin_amdgcn_sched_barrier(0);
            if (t + 2 < nt) {
                if constexpr (BK == 64) asm volatile("s_waitcnt vmcnt(8)" ::: "memory");
                else                    asm volatile("s_waitcnt vmcnt(4)" ::: "memory");
            } else {
                asm volatile("s_waitcnt vmcnt(0)" ::: "memory");
            }
            __builtin_amdgcn_s_barrier();          // single barrier per tile
            __builtin_amdgcn_sched_barrier(0);
        }
        __bf16* tmp = p0; p0 = p1; p1 = p2; p2 = tmp;
    }
}

// ---------------------------------------------------------------------------
// MFMA bf16 GEMM: C[M,N] = A[M,K] @ B[N,K]^T (batched via blockIdx.z),
// with XCD-chunked tile swizzle.
// ---------------------------------------------------------------------------
template<bool OUT_BF16, int BK, int MINW, bool TRI>
__global__ __launch_bounds__(256, MINW) void gemm_mfma(
    const __bf16* __restrict__ A, const __bf16* __restrict__ B, void* __restrict__ Cv,
    int M, int N, int K, int lda, int ldb, int ldc,
    long long sA, long long sB, long long sC)
{
    __shared__ __bf16 lds[TRI ? 768 * BK : 512 * BK];
    const __bf16* Ab = A + (long long)blockIdx.z * sA;
    const __bf16* Bb = B + (long long)blockIdx.z * sB;
    const int tid = threadIdx.x;
    const int w = tid >> 6, lane = tid & 63, quad = lane >> 4, ln = lane & 15;
    int bx, by; swz2d(gridDim.x, gridDim.y, bx, by);
    const int m0 = by * 128, n0 = bx * 128;
    const int wm = (w >> 1) * 64, wn = (w & 1) * 64;

    f32x4 acc[4][4];
#pragma unroll
    for (int i = 0; i < 4; ++i)
#pragma unroll
        for (int j = 0; j < 4; ++j) acc[i][j] = (f32x4){0.f, 0.f, 0.f, 0.f};

    if (TRI) gemm_core_tri<BK>(Ab, Bb, lda, ldb, m0, n0, K, lds, acc);
    else     gemm_core_dbuf<BK>(Ab, Bb, lda, ldb, m0, n0, K, lds, acc);

    if (OUT_BF16) {
        __bf16* Cb = (__bf16*)Cv + (long long)blockIdx.z * sC;
#pragma unroll
        for (int mi = 0; mi < 4; ++mi)
#pragma unroll
            for (int r = 0; r < 4; ++r) {
                size_t row = (size_t)(m0 + wm + mi * 16 + quad * 4 + r);
#pragma unroll
                for (int ni = 0; ni < 4; ++ni)
                    Cb[row * ldc + (n0 + wn + ni * 16 + ln)] = (__bf16)acc[mi][ni][r];
            }
    } else {
        float* Cb = (float*)Cv + (long long)blockIdx.z * sC;
#pragma unroll
        for (int mi = 0; mi < 4; ++mi)
#pragma unroll
            for (int r = 0; r < 4; ++r) {
                size_t row = (size_t)(m0 + wm + mi * 16 + quad * 4 + r);
#pragma unroll
                for (int ni = 0; ni < 4; ++ni)
                    Cb[row * ldc + (n0 + wn + ni * 16 + ln)] = acc[mi][ni][r];
            }
    }
}

// ---------------------------------------------------------------------------
// qlat GEMM with fused Qc scatter: Qc[b][h][s][0..512) = q_nope[h] @ Wk[h]^T
// ---------------------------------------------------------------------------
__global__ __launch_bounds__(256, 3) void gemm_qlat(
    const __bf16* __restrict__ qb, const __bf16* __restrict__ Wkb,
    __bf16* __restrict__ Qc)
{
    __shared__ __bf16 lds[768 * 32];
    const int h = blockIdx.z;
    const __bf16* Ab = qb + (size_t)h * QKD;
    const __bf16* Bb = Wkb + (size_t)h * KVLR * NOPE;
    const int tid = threadIdx.x;
    const int w = tid >> 6, lane = tid & 63, quad = lane >> 4, ln = lane & 15;
    int bx, by; swz2d(gridDim.x, gridDim.y, bx, by);
    const int m0 = by * 128, n0 = bx * 128;
    const int wm = (w >> 1) * 64, wn = (w & 1) * 64;

    f32x4 acc[4][4];
#pragma unroll
    for (int i = 0; i < 4; ++i)
#pragma unroll
        for (int j = 0; j < 4; ++j) acc[i][j] = (f32x4){0.f, 0.f, 0.f, 0.f};

    gemm_core_tri<32>(Ab, Bb, NHD * QKD, NOPE, m0, n0, NOPE, lds, acc);

#pragma unroll
    for (int mi = 0; mi < 4; ++mi)
#pragma unroll
        for (int r = 0; r < 4; ++r) {
            int row = m0 + wm + mi * 16 + quad * 4 + r;   // b*S + s
            int bb = row >> 10, s = row & 1023;
            __bf16* dst = Qc + ((size_t)(bb * NHD + h) * SS + s) * 576;
#pragma unroll
            for (int ni = 0; ni < 4; ++ni)
                dst[n0 + wn + ni * 16 + ln] = (__bf16)acc[mi][ni][r];
        }
}

// ---------------------------------------------------------------------------
// Vh GEMM (R7): Vh[z=b*16+h][128v][1024s] = Wvb[h] @ Kc[b][:, :512]^T.
// ---------------------------------------------------------------------------
__global__ __launch_bounds__(256, 3) void gemm_vh(
    const __bf16* __restrict__ Wvb, const __bf16* __restrict__ Kc,
    __bf16* __restrict__ Vh)
{
    int lin = blockIdx.x + 8 * blockIdx.z;           // 0..255
    lin = (lin & 7) * 32 + (lin >> 3);               // bijective chunk swizzle
    const int z = lin >> 3;
    const int ntile = lin & 7;
    const int b = z >> 4, h = z & 15;

    __shared__ __bf16 lds[768 * 32];
    const __bf16* Ab = Wvb + (size_t)h * VDIM * KVLR;
    const __bf16* Bb = Kc + (size_t)b * SS * 576;
    const int tid = threadIdx.x;
    const int w = tid >> 6, lane = tid & 63, quad = lane >> 4, ln = lane & 15;
    const int m0 = 0, n0 = ntile * 128;
    const int wm = (w >> 1) * 64, wn = (w & 1) * 64;

    f32x4 acc[4][4];
#pragma unroll
    for (int i = 0; i < 4; ++i)
#pragma unroll
        for (int j = 0; j < 4; ++j) acc[i][j] = (f32x4){0.f, 0.f, 0.f, 0.f};

    gemm_core_tri<32>(Ab, Bb, KVLR, 576, m0, n0, KVLR, lds, acc);

    __bf16* Cb = Vh + (size_t)z * VDIM * SS;         // [128][1024]
#pragma unroll
    for (int mi = 0; mi < 4; ++mi)
#pragma unroll
        for (int r = 0; r < 4; ++r) {
            int row = m0 + wm + mi * 16 + quad * 4 + r;
#pragma unroll
            for (int ni = 0; ni < 4; ++ni)
                Cb[(size_t)row * SS + (n0 + wn + ni * 16 + ln)] = (__bf16)acc[mi][ni][r];
        }
}

// ---------------------------------------------------------------------------
// Causal scores GEMM, exact-triangle grid + chunked XCD swizzle.
// ---------------------------------------------------------------------------
__global__ __launch_bounds__(256, 3) void gemm_scores(
    const __bf16* __restrict__ Qc, const __bf16* __restrict__ Kc,
    __bf16* __restrict__ Sc)
{
    int lin = blockIdx.x + 36 * blockIdx.y;          // 0..1151
    lin = (lin & 7) * 144 + (lin >> 3);              // bijective chunk swizzle
    const int z = lin / 36;
    const int i = lin - z * 36;
    int mt = (int)((sqrtf(8.f * i + 1.f) - 1.f) * 0.5f);
    if (mt * (mt + 1) / 2 > i) --mt;
    if ((mt + 1) * (mt + 2) / 2 <= i) ++mt;
    const int nt = i - mt * (mt + 1) / 2;

    const int b = z >> 4;
    __shared__ __bf16 lds[768 * 32];
    const __bf16* Ab = Qc + (size_t)z * SS * 576;
    const __bf16* Bb = Kc + (size_t)b * SS * 576;
    __bf16* Cb = Sc + (size_t)z * SS * SS;
    const int tid = threadIdx.x;
    const int w = tid >> 6, lane = tid & 63, quad = lane >> 4, ln = lane & 15;
    const int m0 = mt * 128, n0 = nt * 128;
    const int wm = (w >> 1) * 64, wn = (w & 1) * 64;

    f32x4 acc[4][4];
#pragma unroll
    for (int i2 = 0; i2 < 4; ++i2)
#pragma unroll
        for (int j = 0; j < 4; ++j) acc[i2][j] = (f32x4){0.f, 0.f, 0.f, 0.f};

    gemm_core_tri<32>(Ab, Bb, 576, 576, m0, n0, 576, lds, acc);

    const float SCL2 = 0.07216878364870323f * 1.4426950408889634f;  // scale*log2e
#pragma unroll
    for (int mi = 0; mi < 4; ++mi)
#pragma unroll
        for (int r = 0; r < 4; ++r) {
            int row = m0 + wm + mi * 16 + quad * 4 + r;
#pragma unroll
            for (int ni = 0; ni < 4; ++ni) {
                int col = n0 + wn + ni * 16 + ln;
                float v = acc[mi][ni][r] * SCL2;
                if (col > row) v = -1e30f;
                Cb[(size_t)row * SS + col] = (__bf16)v;
            }
        }
}

// ---------------------------------------------------------------------------
// Row softmax (exp2 domain). One wave per row, shfl-only reductions.
// ---------------------------------------------------------------------------
__global__ __launch_bounds__(256) void softmax_kernel(__bf16* __restrict__ Sc)
{
    const int z = blockIdx.y;
    const int w = threadIdx.x >> 6, lane = threadIdx.x & 63;
    const int r = blockIdx.x * 4 + w;
    __bf16* row = Sc + (size_t)z * SS * SS + (size_t)r * SS;
    const int ncols = ((r >> 7) + 1) << 7;
    const int i0 = lane * 8, i1 = i0 + 512;
    const bool a0 = i0 < ncols, a1 = i1 < ncols;
    float v[16];
    float lmax = -1e30f;
    if (a0) {
        bf16x8 c = *(const bf16x8*)(row + i0);
#pragma unroll
        for (int j = 0; j < 8; ++j) { v[j] = (float)c[j]; lmax = fmaxf(lmax, v[j]); }
    }
    if (a1) {
        bf16x8 c = *(const bf16x8*)(row + i1);
#pragma unroll
        for (int j = 0; j < 8; ++j) { v[8 + j] = (float)c[j]; lmax = fmaxf(lmax, v[8 + j]); }
    }
#pragma unroll
    for (int off = 1; off < 64; off <<= 1) lmax = fmaxf(lmax, __shfl_xor(lmax, off));
    float lsum = 0.f;
    if (a0) {
#pragma unroll
        for (int j = 0; j < 8; ++j) { v[j] = __builtin_amdgcn_exp2f(v[j] - lmax); lsum += v[j]; }
    }
    if (a1) {
#pragma unroll
        for (int j = 0; j < 8; ++j) { v[8 + j] = __builtin_amdgcn_exp2f(v[8 + j] - lmax); lsum += v[8 + j]; }
    }
#pragma unroll
    for (int off = 1; off < 64; off <<= 1) lsum += __shfl_xor(lsum, off);
    const float inv = 1.f / lsum;
    if (a0) {
        bf16x8 c;
#pragma unroll
        for (int j = 0; j < 8; ++j) c[j] = (__bf16)(v[j] * inv);
        *(bf16x8*)(row + i0) = c;
    }
    if (a1) {
        bf16x8 c;
#pragma unroll
        for (int j = 0; j < 8; ++j) c[j] = (__bf16)(v[8 + j] * inv);
        *(bf16x8*)(row + i1) = c;
    }
}

// ---------------------------------------------------------------------------
// PV GEMM (R7, head-space): ohb[b, s, h*128+v] = P[z] @ Vh[z]^T.
// ---------------------------------------------------------------------------
__global__ __launch_bounds__(256, 3) void gemm_pv(
    const __bf16* __restrict__ Sc, const __bf16* __restrict__ Vh,
    __bf16* __restrict__ ohb)
{
    int lin = blockIdx.x + 8 * blockIdx.y;           // 0..255
    lin = (lin & 7) * 32 + (lin >> 3);               // bijective chunk swizzle
    const int z = lin >> 3;
    const int mt = lin & 7;

    const int b = z >> 4, h = z & 15;
    const int Keff = (mt + 1) * 128;
    __shared__ __bf16 lds[768 * 32];
    const __bf16* Ab = Sc + (size_t)z * SS * SS;
    const __bf16* Bb = Vh + (size_t)z * VDIM * SS;
    const int tid = threadIdx.x;
    const int w = tid >> 6, lane = tid & 63, quad = lane >> 4, ln = lane & 15;
    const int m0 = mt * 128, n0 = 0;
    const int wm = (w >> 1) * 64, wn = (w & 1) * 64;

    f32x4 acc[4][4];
#pragma unroll
    for (int i = 0; i < 4; ++i)
#pragma unroll
        for (int j = 0; j < 4; ++j) acc[i][j] = (f32x4){0.f, 0.f, 0.f, 0.f};

    gemm_core_tri<32>(Ab, Bb, SS, SS, m0, n0, Keff, lds, acc);

#pragma unroll
    for (int mi = 0; mi < 4; ++mi)
#pragma unroll
        for (int r = 0; r < 4; ++r) {
            int row = m0 + wm + mi * 16 + quad * 4 + r;
            __bf16* op = ohb + (size_t)(b * SS + row) * (NHD * VDIM) + h * VDIM;
#pragma unroll
            for (int ni = 0; ni < 4; ++ni)
                op[n0 + wn + ni * 16 + ln] = (__bf16)acc[mi][ni][r];
        }
}

// ---------------------------------------------------------------------------
// Cast helpers
// ---------------------------------------------------------------------------
__global__ __launch_bounds__(256) void castf2b(const float* __restrict__ in,
                                               __bf16* __restrict__ out, int n)
{
    int i = (blockIdx.x * 256 + threadIdx.x) * 4;
    if (i < n) {
        float4 v = *(const float4*)(in + i);
        out[i] = (__bf16)v.x; out[i + 1] = (__bf16)v.y;
        out[i + 2] = (__bf16)v.z; out[i + 3] = (__bf16)v.w;
    }
}

// combined [w_qa(1536); w_kva(576); pad(64)] x 2048 -> bf16
__global__ __launch_bounds__(256) void cast_comb(const float* __restrict__ wqa,
                                                 const float* __restrict__ wkva,
                                                 __bf16* __restrict__ out)
{
    int idx = (blockIdx.x * 256 + threadIdx.x) * 4;
    int row = idx >> 11, col = idx & 2047;
    const float* src;
    if (row < 1536)      src = wqa + (size_t)row * 2048 + col;
    else if (row < 2112) src = wkva + (size_t)(row - 1536) * 2048 + col;
    else {
        out[idx] = (__bf16)0.f; out[idx + 1] = (__bf16)0.f;
        out[idx + 2] = (__bf16)0.f; out[idx + 3] = (__bf16)0.f;
        return;
    }
    float4 v = *(const float4*)src;
    out[idx] = (__bf16)v.x; out[idx + 1] = (__bf16)v.y;
    out[idx + 2] = (__bf16)v.z; out[idx + 3] = (__bf16)v.w;
}

// batched transpose-cast: in[z][R][C] fp32 -> out[z][C][R] bf16
__global__ __launch_bounds__(256) void transpose_cast(const float* __restrict__ in,
                                                      __bf16* __restrict__ out,
                                                      int R, int C)
{
    __shared__ float t[32][33];
    in  += (size_t)blockIdx.z * R * C;
    out += (size_t)blockIdx.z * R * C;
    int c0 = blockIdx.x * 32, r0 = blockIdx.y * 32;
    int tx = threadIdx.x & 31, ty = threadIdx.x >> 5;
#pragma unroll
    for (int i = 0; i < 4; ++i) {
        int r = ty + i * 8;
        t[r][tx] = in[(size_t)(r0 + r) * C + c0 + tx];
    }
    __syncthreads();
#pragma unroll
    for (int i = 0; i < 4; ++i) {
        int rr = ty + i * 8;
        out[(size_t)(c0 + rr) * R + r0 + tx] = (__bf16)t[tx][rr];
    }
}

// ---------------------------------------------------------------------------
// LayerNorm fp32 in (row stride ldx) -> bf16 out (row stride N).
// ---------------------------------------------------------------------------
__global__ __launch_bounds__(256) void ln_kernel(const float* __restrict__ x,
                                                 const float* __restrict__ w,
                                                 __bf16* __restrict__ y, int N, int ldx)
{
    long long row = blockIdx.x;
    const float* xr = x + row * ldx;
    __bf16* yr = y + row * N;
    int tid = threadIdx.x;
    float s = 0.f, ss = 0.f;
    for (int i = tid; i < N; i += 256) { float v = xr[i]; s += v; ss += v * v; }
#pragma unroll
    for (int off = 32; off > 0; off >>= 1) { s += __shfl_down(s, off); ss += __shfl_down(ss, off); }
    __shared__ float rs[4], rss[4];
    __shared__ float smean, sinv;
    int wave = tid >> 6, lane = tid & 63;
    if (lane == 0) { rs[wave] = s; rss[wave] = ss; }
    __syncthreads();
    if (tid == 0) {
        float S = rs[0] + rs[1] + rs[2] + rs[3];
        float Q = rss[0] + rss[1] + rss[2] + rss[3];
        float mean = S / N;
        float var = Q / N - mean * mean;
        smean = mean; sinv = rsqrtf(var + EPSF);
    }
    __syncthreads();
    float mean = smean, inv = sinv;
    for (int i = tid; i < N; i += 256) yr[i] = (__bf16)((xr[i] - mean) * inv * w[i]);
}

// ---------------------------------------------------------------------------
// Per-token prep: Kc[row] = bf16(concat(LN(kva[:512])*w, rope(kva[512:576])))
// kva row stride ld; roped q_pe written straight into Qc cols [512,576).
// ---------------------------------------------------------------------------
__global__ __launch_bounds__(256) void prep_kernel(
    const float* __restrict__ kva, int ld, const float* __restrict__ kvw,
    const float* __restrict__ cosb, const float* __restrict__ sinb,
    __bf16* __restrict__ Kc, const __bf16* __restrict__ q,
    __bf16* __restrict__ Qc)
{
    long long row = blockIdx.x;
    const float* kr = kva + row * ld;
    const float* cr = cosb + row * ROPED;
    const float* sr = sinb + row * ROPED;
    int tid = threadIdx.x;
    float v0 = kr[tid], v1 = kr[tid + 256];
    float s = v0 + v1, ss = v0 * v0 + v1 * v1;
#pragma unroll
    for (int off = 32; off > 0; off >>= 1) { s += __shfl_down(s, off); ss += __shfl_down(ss, off); }
    __shared__ float rs[4], rss[4];
    __shared__ float smean, sinv;
    int wave = tid >> 6, lane = tid & 63;
    if (lane == 0) { rs[wave] = s; rss[wave] = ss; }
    __syncthreads();
    if (tid == 0) {
        float S = rs[0] + rs[1] + rs[2] + rs[3];
        float Q = rss[0] + rss[1] + rss[2] + rss[3];
        float mean = S / KVLR;
        float var = Q / KVLR - mean * mean;
        smean = mean; sinv = rsqrtf(var + EPSF);
    }
    __syncthreads();
    float mean = smean, inv = sinv;
    __bf16* kc = Kc + row * 576;
    kc[tid]       = (__bf16)((v0 - mean) * inv * kvw[tid]);
    kc[tid + 256] = (__bf16)((v1 - mean) * inv * kvw[tid + 256]);
    if (tid < 32) {
        float x1 = kr[KVLR + tid], x2 = kr[KVLR + 32 + tid];
        kc[512 + tid]      = (__bf16)(x1 * cr[tid] - x2 * sr[tid]);
        kc[512 + 32 + tid] = (__bf16)(x2 * cr[32 + tid] + x1 * sr[32 + tid]);
    }
    const int bb = (int)(row >> 10), sp = (int)(row & 1023);
    const __bf16* qr = q + row * (NHD * QKD);
#pragma unroll
    for (int j = 0; j < 2; ++j) {
        int idx = tid + j * 256;
        int h = idx >> 5, p = idx & 31;
        const __bf16* base = qr + h * QKD + NOPE;
        float x1 = (float)base[p], x2 = (float)base[32 + p];
        __bf16* qcb = Qc + ((size_t)(bb * NHD + h) * SS + sp) * 576 + 512;
        qcb[p]      = (__bf16)(x1 * cr[p] - x2 * sr[p]);
        qcb[32 + p] = (__bf16)(x2 * cr[32 + p] + x1 * sr[32 + p]);
    }
}

// ---------------------------------------------------------------------------
extern "C" void kernel_launch(void* const* d_in, const int* in_sizes, int n_in,
                              void* d_out, int out_size, void* d_ws, size_t ws_size,
                              hipStream_t stream)
{
    const float* hidden    = (const float*)d_in[0];
    const float* cosb      = (const float*)d_in[1];
    const float* sinb      = (const float*)d_in[2];
    const float* w_qa      = (const float*)d_in[3];
    const float* q_a_ln_w  = (const float*)d_in[4];
    const float* w_qb      = (const float*)d_in[5];
    const float* w_kva     = (const float*)d_in[6];
    const float* kv_a_ln_w = (const float*)d_in[7];
    const float* W_UK_T    = (const float*)d_in[8];
    const float* W_UV      = (const float*)d_in[9];
    const float* w_o       = (const float*)d_in[10];
    float* out = (float*)d_out;

    const int M = BB * SS;  // 2048
    // ---- HEAD region: transient buffers, later aliased by Sc (67.1 MB) ----
    float*  qakva = (float*)d_ws;
    __bf16* Xb    = (__bf16*)(qakva + (size_t)M * NCOMB);
    __bf16* qab   = Xb    + (size_t)M * HH;
    __bf16* qb    = qab   + (size_t)M * QLR;
    __bf16* qlatb = qb    + (size_t)M * NHD * QKD;   // slot kept (unused now)
    __bf16* Sc    = (__bf16*)d_ws;                    // aliases head after qlat
    // ---- TAIL region: persistent ----
    __bf16* Kc    = qlatb + (size_t)M * NHD * KVLR;   // M*576
    __bf16* Qc    = Kc    + (size_t)M * 576;          // M*9216
    __bf16* Vt    = Qc    + (size_t)M * NHD * 576;    // 2*512*1024 (unused)
    __bf16* ctxb  = Vt    + (size_t)BB * 512 * SS;    // M*8192: Vh lives here
    __bf16* Vh    = ctxb;                             // 32*128*1024 bf16 = 8MB
    __bf16* ohb   = ctxb  + (size_t)M * NHD * KVLR;   // M*2048
    __bf16* w_cmb = ohb   + (size_t)M * HH;           // 2176*2048
    __bf16* w_qbb = w_cmb + (size_t)NCOMB * HH;       // 3072*1536
    __bf16* Wkb   = w_qbb + (size_t)NHD * QKD * QLR;  // 16*512*128
    __bf16* Wvb   = Wkb   + (size_t)NHD * KVLR * NOPE;// 16*128*512
    __bf16* w_ob  = Wvb   + (size_t)NHD * VDIM * KVLR;// 2048*2048

    dim3 blk(256);

    // --- casts ---
    castf2b<<<dim3((M * HH) / 1024), blk, 0, stream>>>(hidden, Xb, M * HH);
    cast_comb<<<dim3((NCOMB * HH) / 1024), blk, 0, stream>>>(w_qa, w_kva, w_cmb);
    castf2b<<<dim3((NHD * QKD * QLR) / 1024), blk, 0, stream>>>(w_qb, w_qbb, NHD * QKD * QLR);
    castf2b<<<dim3((HH * HH) / 1024), blk, 0, stream>>>(w_o, w_ob, HH * HH);
    transpose_cast<<<dim3(KVLR / 32, NOPE / 32, NHD), blk, 0, stream>>>(W_UK_T, Wkb, NOPE, KVLR);
    transpose_cast<<<dim3(VDIM / 32, KVLR / 32, NHD), blk, 0, stream>>>(W_UV, Wvb, KVLR, VDIM);

    // 1+4 fused: qakva = Xb @ [w_qa; w_kva]^T   (2048 x 2176 x 2048)
    gemm_mfma<false, 64, 2, false><<<dim3(NCOMB / 128, M / 128, 1), blk, 0, stream>>>(
        Xb, w_cmb, qakva, M, NCOMB, HH, HH, HH, NCOMB, 0, 0, 0);
    // 2. qab = bf16(LN(qakva[:, :1536]))
    ln_kernel<<<dim3(M), blk, 0, stream>>>(qakva, q_a_ln_w, qab, QLR, NCOMB);
    // 3. qb = qab @ w_qb^T (bf16)              (2048 x 3072 x 1536)
    gemm_mfma<true, 64, 2, false><<<dim3(NHD * QKD / 128, M / 128, 1), blk, 0, stream>>>(
        qab, w_qbb, qb, M, NHD * QKD, QLR, QLR, QLR, NHD * QKD, 0, 0, 0);
    // 5. Kc = [LN(kv_c), rope(k_pe)] bf16; roped q_pe -> Qc[...,512:576)
    prep_kernel<<<dim3(M), blk, 0, stream>>>(qakva + QLR, NCOMB, kv_a_ln_w,
                                             cosb, sinb, Kc, qb, Qc);
    // 5b. Vh[z] = Wvb[h] @ Kc[b][:, :512]^T   (32 x [128 x 1024 x 512])
    gemm_vh<<<dim3(8, 1, 32), blk, 0, stream>>>(Wvb, Kc, Vh);
    // 6. Qc[...,0:512) = q_nope[h] @ Wkb[h]^T  (16 x [2048 x 512 x 128])
    gemm_qlat<<<dim3(KVLR / 128, M / 128, NHD), blk, 0, stream>>>(qb, Wkb, Qc);
    // 8a. Sc = causal scores, exact triangle grid (1152 blocks)
    gemm_scores<<<dim3(36, 32), blk, 0, stream>>>(Qc, Kc, Sc);
    // 8b. row softmax in place
    softmax_kernel<<<dim3(SS / 4, 32), blk, 0, stream>>>(Sc);
    // 8c. ohb = P @ Vh^T (head-space PV, causal k-bound)
    gemm_pv<<<dim3(8, 32), blk, 0, stream>>>(Sc, Vh, ohb);
    // 10. out = ohb @ w_o^T (fp32)             (2048 x 2048 x 2048)
    gemm_mfma<false, 64, 2, false><<<dim3(HH / 128, M / 128, 1), blk, 0, stream>>>(
        ohb, w_ob, out, M, HH, NHD * VDIM, NHD * VDIM, NHD * VDIM, HH, 0, 0, 0);
}

// Round 10
// 298.807 us; speedup vs baseline: 1.0447x; 1.0447x over previous
//
#include <hip/hip_runtime.h>
#include <hip/hip_bf16.h>
#include <math.h>

#define BB 2
#define SS 1024
#define HH 2048
#define NHD 16
#define NOPE 128
#define ROPED 64
#define VDIM 128
#define QKD 192
#define QLR 1536
#define KVLR 512
#define EPSF 1e-5f
#define NCOMB 2176   // QLR + 576 kv + 64 pad

typedef __bf16 bf16x8 __attribute__((ext_vector_type(8)));
typedef float  f32x4  __attribute__((ext_vector_type(4)));

__device__ __forceinline__ void gload_lds16(const __bf16* g, __bf16* l) {
    __builtin_amdgcn_global_load_lds(
        (const __attribute__((address_space(1))) void*)g,
        (__attribute__((address_space(3))) void*)l, 16, 0, 0);
}

// XCD-chunked bijective tile swizzle (T1, validated R6: FETCH drop + ~8 µs).
__device__ __forceinline__ void swz2d(int nx, int ny, int& bx, int& by) {
    int T = nx * ny;
    int lin = blockIdx.x + nx * blockIdx.y;
    if ((T & 7) == 0) {
        int q = T >> 3;
        lin = (lin & 7) * q + (lin >> 3);
    }
    bx = lin % nx;
    by = lin / nx;
}

// ---------------------------------------------------------------------------
// Double-buffered 2-barrier core (R1 schedule, proven): for dense big-K GEMMs.
// XOR swizzle (both-sides involution, verified): BK=64 chunk^=row&7.
// ---------------------------------------------------------------------------
template<int BK>
__device__ __forceinline__ void gemm_core_dbuf(
    const __bf16* __restrict__ Ab, const __bf16* __restrict__ Bb,
    int lda, int ldb, int m0, int n0, int K, __bf16* lds, f32x4 acc[4][4])
{
    constexpr int CH    = BK / 8;
    constexpr int LPT   = CH / 2;
    constexpr int BUFE  = 256 * BK;
    constexpr int BOFF  = 128 * BK;
    constexpr int RSTEP = 2048 / BK;
    const int tid = threadIdx.x;
    const int w = tid >> 6, lane = tid & 63, quad = lane >> 4, ln = lane & 15;
    const int wm = (w >> 1) * 64, wn = (w & 1) * 64;
    const int nt = K / BK;

    const int sr  = tid / CH;
    const int spc = tid % CH;
    const int sc  = (BK == 64) ? (spc ^ (sr & 7)) : (spc ^ ((sr >> 1) & 3));
    const __bf16* gA = Ab + (size_t)(m0 + sr) * lda + sc * 8;
    const __bf16* gB = Bb + (size_t)(n0 + sr) * ldb + sc * 8;

    const int swm = (BK == 64) ? ((wm + ln) & 7) : (((wm + ln) >> 1) & 3);
    const int swn = (BK == 64) ? ((wn + ln) & 7) : (((wn + ln) >> 1) & 3);

    auto stage = [&](int buf, int kk) {
        __bf16* la = lds + buf * BUFE + w * 512;
        __bf16* lb = la + BOFF;
        const __bf16* ga = gA + kk;
        const __bf16* gb = gB + kk;
#pragma unroll
        for (int i = 0; i < LPT; ++i) {
            gload_lds16(ga + (size_t)(i * RSTEP) * lda, la + i * 2048);
            gload_lds16(gb + (size_t)(i * RSTEP) * ldb, lb + i * 2048);
        }
    };
    auto wait_stage = [&]() {
        if constexpr (BK == 64) asm volatile("s_waitcnt vmcnt(8)" ::: "memory");
        else                    asm volatile("s_waitcnt vmcnt(4)" ::: "memory");
    };

    stage(0, 0);
    stage(1, BK);
    wait_stage();
    __builtin_amdgcn_s_barrier();
    __builtin_amdgcn_sched_barrier(0);

    for (int t = 0; t < nt; ++t) {
        const int cur = t & 1;
        const __bf16* bufA = lds + cur * BUFE;
        const __bf16* bufB = bufA + BOFF;
        bf16x8 af[BK / 32][4], bv[BK / 32][4];
#pragma unroll
        for (int ks = 0; ks < BK / 32; ++ks)
#pragma unroll
            for (int i = 0; i < 4; ++i) {
                af[ks][i] = *(const bf16x8*)
                    &bufA[(wm + ln) * BK + i * 16 * BK + (((ks * 4 + quad) ^ swm) << 3)];
                bv[ks][i] = *(const bf16x8*)
                    &bufB[(wn + ln) * BK + i * 16 * BK + (((ks * 4 + quad) ^ swn) << 3)];
            }
        __builtin_amdgcn_s_setprio(1);
#pragma unroll
        for (int ks = 0; ks < BK / 32; ++ks)
#pragma unroll
            for (int mi = 0; mi < 4; ++mi)
#pragma unroll
                for (int ni = 0; ni < 4; ++ni)
                    acc[mi][ni] = __builtin_amdgcn_mfma_f32_16x16x32_bf16(
                        af[ks][mi], bv[ks][ni], acc[mi][ni], 0, 0, 0);
        __builtin_amdgcn_s_setprio(0);
        if (t + 1 < nt) {
            __builtin_amdgcn_sched_barrier(0);
            asm volatile("" ::: "memory");
            __builtin_amdgcn_s_barrier();          // (a) reads of buf[cur] done
            asm volatile("" ::: "memory");
            if (t + 2 < nt) {
                stage(cur, (t + 2) * BK);
                wait_stage();
            } else {
                asm volatile("s_waitcnt vmcnt(0)" ::: "memory");
            }
            __builtin_amdgcn_s_barrier();          // (b) publish t+1
            __builtin_amdgcn_sched_barrier(0);
        }
    }
}

// ---------------------------------------------------------------------------
// Triple-buffered 1-barrier core (BK=32: 48 KB LDS -> 3 blocks/CU).
// Proven R4; R8 compiler-scheduled ds_read->MFMA (neutral, kept).
// ---------------------------------------------------------------------------
template<int BK>
__device__ __forceinline__ void gemm_core_tri(
    const __bf16* __restrict__ Ab, const __bf16* __restrict__ Bb,
    int lda, int ldb, int m0, int n0, int K, __bf16* lds, f32x4 acc[4][4])
{
    constexpr int CH    = BK / 8;
    constexpr int LPT   = CH / 2;
    constexpr int BUFE  = 256 * BK;
    constexpr int BOFF  = 128 * BK;
    constexpr int RSTEP = 2048 / BK;
    const int tid = threadIdx.x;
    const int w = tid >> 6, lane = tid & 63, quad = lane >> 4, ln = lane & 15;
    const int wm = (w >> 1) * 64, wn = (w & 1) * 64;
    const int nt = K / BK;

    const int sr  = tid / CH;
    const int spc = tid % CH;
    const int sc  = (BK == 64) ? (spc ^ (sr & 7)) : (spc ^ ((sr >> 1) & 3));
    const __bf16* gA = Ab + (size_t)(m0 + sr) * lda + sc * 8;
    const __bf16* gB = Bb + (size_t)(n0 + sr) * ldb + sc * 8;

    const int swm = (BK == 64) ? ((wm + ln) & 7) : (((wm + ln) >> 1) & 3);
    const int swn = (BK == 64) ? ((wn + ln) & 7) : (((wn + ln) >> 1) & 3);

    auto stage = [&](__bf16* base, int kk) {
        __bf16* la = base + w * 512;
        __bf16* lb = la + BOFF;
        const __bf16* ga = gA + kk;
        const __bf16* gb = gB + kk;
#pragma unroll
        for (int i = 0; i < LPT; ++i) {
            gload_lds16(ga + (size_t)(i * RSTEP) * lda, la + i * 2048);
            gload_lds16(gb + (size_t)(i * RSTEP) * ldb, lb + i * 2048);
        }
    };

    __bf16* p0 = lds;               // tile t
    __bf16* p1 = lds + BUFE;        // tile t+1
    __bf16* p2 = lds + 2 * BUFE;    // stage target (tile t+2)

    stage(p0, 0);
    stage(p1, BK);
    if constexpr (BK == 64) asm volatile("s_waitcnt vmcnt(8)" ::: "memory");
    else                    asm volatile("s_waitcnt vmcnt(4)" ::: "memory");
    __builtin_amdgcn_s_barrier();
    __builtin_amdgcn_sched_barrier(0);

    for (int t = 0; t < nt; ++t) {
        if (t + 2 < nt) stage(p2, (t + 2) * BK);   // issue global loads first
        bf16x8 af[BK / 32][4], bv[BK / 32][4];
#pragma unroll
        for (int ks = 0; ks < BK / 32; ++ks)
#pragma unroll
            for (int i = 0; i < 4; ++i) {
                af[ks][i] = *(const bf16x8*)
                    &p0[(wm + ln) * BK + i * 16 * BK + (((ks * 4 + quad) ^ swm) << 3)];
                bv[ks][i] = *(const bf16x8*)
                    &p0[BOFF + (wn + ln) * BK + i * 16 * BK + (((ks * 4 + quad) ^ swn) << 3)];
            }
        __builtin_amdgcn_s_setprio(1);
#pragma unroll
        for (int ks = 0; ks < BK / 32; ++ks)
#pragma unroll
            for (int mi = 0; mi < 4; ++mi)
#pragma unroll
                for (int ni = 0; ni < 4; ++ni)
                    acc[mi][ni] = __builtin_amdgcn_mfma_f32_16x16x32_bf16(
                        af[ks][mi], bv[ks][ni], acc[mi][ni], 0, 0, 0);
        __builtin_amdgcn_s_setprio(0);
        if (t + 1 < nt) {
            __builtin_amdgcn_sched_barrier(0);
            if (t + 2 < nt) {
                if constexpr (BK == 64) asm volatile("s_waitcnt vmcnt(8)" ::: "memory");
                else                    asm volatile("s_waitcnt vmcnt(4)" ::: "memory");
            } else {
                asm volatile("s_waitcnt vmcnt(0)" ::: "memory");
            }
            __builtin_amdgcn_s_barrier();          // single barrier per tile
            __builtin_amdgcn_sched_barrier(0);
        }
        __bf16* tmp = p0; p0 = p1; p1 = p2; p2 = tmp;
    }
}

// ---------------------------------------------------------------------------
// MFMA bf16 GEMM: C[M,N] = A[M,K] @ B[N,K]^T (batched via blockIdx.z),
// with XCD-chunked tile swizzle.
// ---------------------------------------------------------------------------
template<bool OUT_BF16, int BK, int MINW, bool TRI>
__global__ __launch_bounds__(256, MINW) void gemm_mfma(
    const __bf16* __restrict__ A, const __bf16* __restrict__ B, void* __restrict__ Cv,
    int M, int N, int K, int lda, int ldb, int ldc,
    long long sA, long long sB, long long sC)
{
    __shared__ __bf16 lds[TRI ? 768 * BK : 512 * BK];
    const __bf16* Ab = A + (long long)blockIdx.z * sA;
    const __bf16* Bb = B + (long long)blockIdx.z * sB;
    const int tid = threadIdx.x;
    const int w = tid >> 6, lane = tid & 63, quad = lane >> 4, ln = lane & 15;
    int bx, by; swz2d(gridDim.x, gridDim.y, bx, by);
    const int m0 = by * 128, n0 = bx * 128;
    const int wm = (w >> 1) * 64, wn = (w & 1) * 64;

    f32x4 acc[4][4];
#pragma unroll
    for (int i = 0; i < 4; ++i)
#pragma unroll
        for (int j = 0; j < 4; ++j) acc[i][j] = (f32x4){0.f, 0.f, 0.f, 0.f};

    if (TRI) gemm_core_tri<BK>(Ab, Bb, lda, ldb, m0, n0, K, lds, acc);
    else     gemm_core_dbuf<BK>(Ab, Bb, lda, ldb, m0, n0, K, lds, acc);

    if (OUT_BF16) {
        __bf16* Cb = (__bf16*)Cv + (long long)blockIdx.z * sC;
#pragma unroll
        for (int mi = 0; mi < 4; ++mi)
#pragma unroll
            for (int r = 0; r < 4; ++r) {
                size_t row = (size_t)(m0 + wm + mi * 16 + quad * 4 + r);
#pragma unroll
                for (int ni = 0; ni < 4; ++ni)
                    Cb[row * ldc + (n0 + wn + ni * 16 + ln)] = (__bf16)acc[mi][ni][r];
            }
    } else {
        float* Cb = (float*)Cv + (long long)blockIdx.z * sC;
#pragma unroll
        for (int mi = 0; mi < 4; ++mi)
#pragma unroll
            for (int r = 0; r < 4; ++r) {
                size_t row = (size_t)(m0 + wm + mi * 16 + quad * 4 + r);
#pragma unroll
                for (int ni = 0; ni < 4; ++ni)
                    Cb[row * ldc + (n0 + wn + ni * 16 + ln)] = acc[mi][ni][r];
            }
    }
}

// ---------------------------------------------------------------------------
// Kh GEMM (R9): Khb[z=b*16+h][s][0..128) = Kc[b][:, :512] @ Wuk[h]^T.
// A = Kc[b] (lda 576), B = Wuk[h] raw [128 nope][512 lat] (ldb 512, no
// transpose needed). M=1024(s), N=128 (single n-tile), K=512. Output row
// stride 192 (cols 128..191 hold k_pe, written by prep). Grid (8,1,32):
// lin -> (mt, z) chunk-swizzled so each XCD reuses one Kc[b] from L2.
// ---------------------------------------------------------------------------
__global__ __launch_bounds__(256, 3) void gemm_kh(
    const __bf16* __restrict__ Kc, const __bf16* __restrict__ Wuk,
    __bf16* __restrict__ Khb)
{
    int lin = blockIdx.x + 8 * blockIdx.z;           // 0..255
    lin = (lin & 7) * 32 + (lin >> 3);               // bijective chunk swizzle
    const int z = lin >> 3;
    const int mt = lin & 7;
    const int b = z >> 4, h = z & 15;

    __shared__ __bf16 lds[768 * 32];
    const __bf16* Ab = Kc + (size_t)b * SS * 576;
    const __bf16* Bb = Wuk + (size_t)h * NOPE * KVLR;
    const int tid = threadIdx.x;
    const int w = tid >> 6, lane = tid & 63, quad = lane >> 4, ln = lane & 15;
    const int m0 = mt * 128, n0 = 0;
    const int wm = (w >> 1) * 64, wn = (w & 1) * 64;

    f32x4 acc[4][4];
#pragma unroll
    for (int i = 0; i < 4; ++i)
#pragma unroll
        for (int j = 0; j < 4; ++j) acc[i][j] = (f32x4){0.f, 0.f, 0.f, 0.f};

    gemm_core_tri<32>(Ab, Bb, 576, KVLR, m0, n0, KVLR, lds, acc);

    __bf16* Cb = Khb + (size_t)z * SS * QKD;         // [1024][192]
#pragma unroll
    for (int mi = 0; mi < 4; ++mi)
#pragma unroll
        for (int r = 0; r < 4; ++r) {
            int row = m0 + wm + mi * 16 + quad * 4 + r;
#pragma unroll
            for (int ni = 0; ni < 4; ++ni)
                Cb[(size_t)row * QKD + (n0 + wn + ni * 16 + ln)] = (__bf16)acc[mi][ni][r];
        }
}

// ---------------------------------------------------------------------------
// Vh GEMM (R7): Vh[z=b*16+h][128v][1024s] = Wvb[h] @ Kc[b][:, :512]^T.
// ---------------------------------------------------------------------------
__global__ __launch_bounds__(256, 3) void gemm_vh(
    const __bf16* __restrict__ Wvb, const __bf16* __restrict__ Kc,
    __bf16* __restrict__ Vh)
{
    int lin = blockIdx.x + 8 * blockIdx.z;           // 0..255
    lin = (lin & 7) * 32 + (lin >> 3);               // bijective chunk swizzle
    const int z = lin >> 3;
    const int ntile = lin & 7;
    const int b = z >> 4, h = z & 15;

    __shared__ __bf16 lds[768 * 32];
    const __bf16* Ab = Wvb + (size_t)h * VDIM * KVLR;
    const __bf16* Bb = Kc + (size_t)b * SS * 576;
    const int tid = threadIdx.x;
    const int w = tid >> 6, lane = tid & 63, quad = lane >> 4, ln = lane & 15;
    const int m0 = 0, n0 = ntile * 128;
    const int wm = (w >> 1) * 64, wn = (w & 1) * 64;

    f32x4 acc[4][4];
#pragma unroll
    for (int i = 0; i < 4; ++i)
#pragma unroll
        for (int j = 0; j < 4; ++j) acc[i][j] = (f32x4){0.f, 0.f, 0.f, 0.f};

    gemm_core_tri<32>(Ab, Bb, KVLR, 576, m0, n0, KVLR, lds, acc);

    __bf16* Cb = Vh + (size_t)z * VDIM * SS;         // [128][1024]
#pragma unroll
    for (int mi = 0; mi < 4; ++mi)
#pragma unroll
        for (int r = 0; r < 4; ++r) {
            int row = m0 + wm + mi * 16 + quad * 4 + r;
#pragma unroll
            for (int ni = 0; ni < 4; ++ni)
                Cb[(size_t)row * SS + (n0 + wn + ni * 16 + ln)] = (__bf16)acc[mi][ni][r];
        }
}

// ---------------------------------------------------------------------------
// Causal scores GEMM (R9): Sc[z] = (q[h] @ Khb[z]^T) * scale, K=192. A is a
// strided VIEW of qb (row stride 3072, head offset h*192): q_nope cols
// 0..127, roped q_pe cols 128..191. qb lives in the TAIL (R9-fix: must
// survive Sc writes — Sc aliases only dead head scratch now).
// ---------------------------------------------------------------------------
__global__ __launch_bounds__(256, 3) void gemm_scores(
    const __bf16* __restrict__ qb, const __bf16* __restrict__ Khb,
    __bf16* __restrict__ Sc)
{
    int lin = blockIdx.x + 36 * blockIdx.y;          // 0..1151
    lin = (lin & 7) * 144 + (lin >> 3);              // bijective chunk swizzle
    const int z = lin / 36;
    const int i = lin - z * 36;
    int mt = (int)((sqrtf(8.f * i + 1.f) - 1.f) * 0.5f);
    if (mt * (mt + 1) / 2 > i) --mt;
    if ((mt + 1) * (mt + 2) / 2 <= i) ++mt;
    const int nt = i - mt * (mt + 1) / 2;

    const int b = z >> 4, h = z & 15;
    __shared__ __bf16 lds[768 * 32];
    const __bf16* Ab = qb + (size_t)b * SS * (NHD * QKD) + (size_t)h * QKD;
    const __bf16* Bb = Khb + (size_t)z * SS * QKD;
    __bf16* Cb = Sc + (size_t)z * SS * SS;
    const int tid = threadIdx.x;
    const int w = tid >> 6, lane = tid & 63, quad = lane >> 4, ln = lane & 15;
    const int m0 = mt * 128, n0 = nt * 128;
    const int wm = (w >> 1) * 64, wn = (w & 1) * 64;

    f32x4 acc[4][4];
#pragma unroll
    for (int i2 = 0; i2 < 4; ++i2)
#pragma unroll
        for (int j = 0; j < 4; ++j) acc[i2][j] = (f32x4){0.f, 0.f, 0.f, 0.f};

    gemm_core_tri<32>(Ab, Bb, NHD * QKD, QKD, m0, n0, QKD, lds, acc);

    const float SCL2 = 0.07216878364870323f * 1.4426950408889634f;  // scale*log2e
#pragma unroll
    for (int mi = 0; mi < 4; ++mi)
#pragma unroll
        for (int r = 0; r < 4; ++r) {
            int row = m0 + wm + mi * 16 + quad * 4 + r;
#pragma unroll
            for (int ni = 0; ni < 4; ++ni) {
                int col = n0 + wn + ni * 16 + ln;
                float v = acc[mi][ni][r] * SCL2;
                if (col > row) v = -1e30f;
                Cb[(size_t)row * SS + col] = (__bf16)v;
            }
        }
}

// ---------------------------------------------------------------------------
// Row softmax (exp2 domain). One wave per row, shfl-only reductions.
// ---------------------------------------------------------------------------
__global__ __launch_bounds__(256) void softmax_kernel(__bf16* __restrict__ Sc)
{
    const int z = blockIdx.y;
    const int w = threadIdx.x >> 6, lane = threadIdx.x & 63;
    const int r = blockIdx.x * 4 + w;
    __bf16* row = Sc + (size_t)z * SS * SS + (size_t)r * SS;
    const int ncols = ((r >> 7) + 1) << 7;
    const int i0 = lane * 8, i1 = i0 + 512;
    const bool a0 = i0 < ncols, a1 = i1 < ncols;
    float v[16];
    float lmax = -1e30f;
    if (a0) {
        bf16x8 c = *(const bf16x8*)(row + i0);
#pragma unroll
        for (int j = 0; j < 8; ++j) { v[j] = (float)c[j]; lmax = fmaxf(lmax, v[j]); }
    }
    if (a1) {
        bf16x8 c = *(const bf16x8*)(row + i1);
#pragma unroll
        for (int j = 0; j < 8; ++j) { v[8 + j] = (float)c[j]; lmax = fmaxf(lmax, v[8 + j]); }
    }
#pragma unroll
    for (int off = 1; off < 64; off <<= 1) lmax = fmaxf(lmax, __shfl_xor(lmax, off));
    float lsum = 0.f;
    if (a0) {
#pragma unroll
        for (int j = 0; j < 8; ++j) { v[j] = __builtin_amdgcn_exp2f(v[j] - lmax); lsum += v[j]; }
    }
    if (a1) {
#pragma unroll
        for (int j = 0; j < 8; ++j) { v[8 + j] = __builtin_amdgcn_exp2f(v[8 + j] - lmax); lsum += v[8 + j]; }
    }
#pragma unroll
    for (int off = 1; off < 64; off <<= 1) lsum += __shfl_xor(lsum, off);
    const float inv = 1.f / lsum;
    if (a0) {
        bf16x8 c;
#pragma unroll
        for (int j = 0; j < 8; ++j) c[j] = (__bf16)(v[j] * inv);
        *(bf16x8*)(row + i0) = c;
    }
    if (a1) {
        bf16x8 c;
#pragma unroll
        for (int j = 0; j < 8; ++j) c[j] = (__bf16)(v[8 + j] * inv);
        *(bf16x8*)(row + i1) = c;
    }
}

// ---------------------------------------------------------------------------
// PV GEMM (R7, head-space): ohb[b, s, h*128+v] = P[z] @ Vh[z]^T.
// ---------------------------------------------------------------------------
__global__ __launch_bounds__(256, 3) void gemm_pv(
    const __bf16* __restrict__ Sc, const __bf16* __restrict__ Vh,
    __bf16* __restrict__ ohb)
{
    int lin = blockIdx.x + 8 * blockIdx.y;           // 0..255
    lin = (lin & 7) * 32 + (lin >> 3);               // bijective chunk swizzle
    const int z = lin >> 3;
    const int mt = lin & 7;

    const int b = z >> 4, h = z & 15;
    const int Keff = (mt + 1) * 128;
    __shared__ __bf16 lds[768 * 32];
    const __bf16* Ab = Sc + (size_t)z * SS * SS;
    const __bf16* Bb = Vh + (size_t)z * VDIM * SS;
    const int tid = threadIdx.x;
    const int w = tid >> 6, lane = tid & 63, quad = lane >> 4, ln = lane & 15;
    const int m0 = mt * 128, n0 = 0;
    const int wm = (w >> 1) * 64, wn = (w & 1) * 64;

    f32x4 acc[4][4];
#pragma unroll
    for (int i = 0; i < 4; ++i)
#pragma unroll
        for (int j = 0; j < 4; ++j) acc[i][j] = (f32x4){0.f, 0.f, 0.f, 0.f};

    gemm_core_tri<32>(Ab, Bb, SS, SS, m0, n0, Keff, lds, acc);

#pragma unroll
    for (int mi = 0; mi < 4; ++mi)
#pragma unroll
        for (int r = 0; r < 4; ++r) {
            int row = m0 + wm + mi * 16 + quad * 4 + r;
            __bf16* op = ohb + (size_t)(b * SS + row) * (NHD * VDIM) + h * VDIM;
#pragma unroll
            for (int ni = 0; ni < 4; ++ni)
                op[n0 + wn + ni * 16 + ln] = (__bf16)acc[mi][ni][r];
        }
}

// ---------------------------------------------------------------------------
// Cast helpers
// ---------------------------------------------------------------------------
__global__ __launch_bounds__(256) void castf2b(const float* __restrict__ in,
                                               __bf16* __restrict__ out, int n)
{
    int i = (blockIdx.x * 256 + threadIdx.x) * 4;
    if (i < n) {
        float4 v = *(const float4*)(in + i);
        out[i] = (__bf16)v.x; out[i + 1] = (__bf16)v.y;
        out[i + 2] = (__bf16)v.z; out[i + 3] = (__bf16)v.w;
    }
}

// combined [w_qa(1536); w_kva(576); pad(64)] x 2048 -> bf16
__global__ __launch_bounds__(256) void cast_comb(const float* __restrict__ wqa,
                                                 const float* __restrict__ wkva,
                                                 __bf16* __restrict__ out)
{
    int idx = (blockIdx.x * 256 + threadIdx.x) * 4;
    int row = idx >> 11, col = idx & 2047;
    const float* src;
    if (row < 1536)      src = wqa + (size_t)row * 2048 + col;
    else if (row < 2112) src = wkva + (size_t)(row - 1536) * 2048 + col;
    else {
        out[idx] = (__bf16)0.f; out[idx + 1] = (__bf16)0.f;
        out[idx + 2] = (__bf16)0.f; out[idx + 3] = (__bf16)0.f;
        return;
    }
    float4 v = *(const float4*)src;
    out[idx] = (__bf16)v.x; out[idx + 1] = (__bf16)v.y;
    out[idx + 2] = (__bf16)v.z; out[idx + 3] = (__bf16)v.w;
}

// batched transpose-cast: in[z][R][C] fp32 -> out[z][C][R] bf16
__global__ __launch_bounds__(256) void transpose_cast(const float* __restrict__ in,
                                                      __bf16* __restrict__ out,
                                                      int R, int C)
{
    __shared__ float t[32][33];
    in  += (size_t)blockIdx.z * R * C;
    out += (size_t)blockIdx.z * R * C;
    int c0 = blockIdx.x * 32, r0 = blockIdx.y * 32;
    int tx = threadIdx.x & 31, ty = threadIdx.x >> 5;
#pragma unroll
    for (int i = 0; i < 4; ++i) {
        int r = ty + i * 8;
        t[r][tx] = in[(size_t)(r0 + r) * C + c0 + tx];
    }
    __syncthreads();
#pragma unroll
    for (int i = 0; i < 4; ++i) {
        int rr = ty + i * 8;
        out[(size_t)(c0 + rr) * R + r0 + tx] = (__bf16)t[tx][rr];
    }
}

// ---------------------------------------------------------------------------
// LayerNorm fp32 in (row stride ldx) -> bf16 out (row stride N).
// ---------------------------------------------------------------------------
__global__ __launch_bounds__(256) void ln_kernel(const float* __restrict__ x,
                                                 const float* __restrict__ w,
                                                 __bf16* __restrict__ y, int N, int ldx)
{
    long long row = blockIdx.x;
    const float* xr = x + row * ldx;
    __bf16* yr = y + row * N;
    int tid = threadIdx.x;
    float s = 0.f, ss = 0.f;
    for (int i = tid; i < N; i += 256) { float v = xr[i]; s += v; ss += v * v; }
#pragma unroll
    for (int off = 32; off > 0; off >>= 1) { s += __shfl_down(s, off); ss += __shfl_down(ss, off); }
    __shared__ float rs[4], rss[4];
    __shared__ float smean, sinv;
    int wave = tid >> 6, lane = tid & 63;
    if (lane == 0) { rs[wave] = s; rss[wave] = ss; }
    __syncthreads();
    if (tid == 0) {
        float S = rs[0] + rs[1] + rs[2] + rs[3];
        float Q = rss[0] + rss[1] + rss[2] + rss[3];
        float mean = S / N;
        float var = Q / N - mean * mean;
        smean = mean; sinv = rsqrtf(var + EPSF);
    }
    __syncthreads();
    float mean = smean, inv = sinv;
    for (int i = tid; i < N; i += 256) yr[i] = (__bf16)((xr[i] - mean) * inv * w[i]);
}

// ---------------------------------------------------------------------------
// Per-token prep (R9): Kc[row] = bf16(concat(LN(kva[:512])*w, rope(k_pe)));
// ropes q_pe IN PLACE in qb; broadcasts roped k_pe into Khb[z][sp][128..192)
// for all 16 heads (cols 0..127 of Khb are written by gemm_kh — disjoint).
// ---------------------------------------------------------------------------
__global__ __launch_bounds__(256) void prep_kernel(
    const float* __restrict__ kva, int ld, const float* __restrict__ kvw,
    const float* __restrict__ cosb, const float* __restrict__ sinb,
    __bf16* __restrict__ Kc, __bf16* __restrict__ q,
    __bf16* __restrict__ Khb)
{
    long long row = blockIdx.x;
    const float* kr = kva + row * ld;
    const float* cr = cosb + row * ROPED;
    const float* sr = sinb + row * ROPED;
    int tid = threadIdx.x;
    float v0 = kr[tid], v1 = kr[tid + 256];
    float s = v0 + v1, ss = v0 * v0 + v1 * v1;
#pragma unroll
    for (int off = 32; off > 0; off >>= 1) { s += __shfl_down(s, off); ss += __shfl_down(ss, off); }
    __shared__ float rs[4], rss[4];
    __shared__ float smean, sinv;
    __shared__ float kpe_s[64];
    int wave = tid >> 6, lane = tid & 63;
    if (lane == 0) { rs[wave] = s; rss[wave] = ss; }
    __syncthreads();
    if (tid == 0) {
        float S = rs[0] + rs[1] + rs[2] + rs[3];
        float Q = rss[0] + rss[1] + rss[2] + rss[3];
        float mean = S / KVLR;
        float var = Q / KVLR - mean * mean;
        smean = mean; sinv = rsqrtf(var + EPSF);
    }
    __syncthreads();
    float mean = smean, inv = sinv;
    __bf16* kc = Kc + row * 576;
    kc[tid]       = (__bf16)((v0 - mean) * inv * kvw[tid]);
    kc[tid + 256] = (__bf16)((v1 - mean) * inv * kvw[tid + 256]);
    if (tid < 32) {
        float x1 = kr[KVLR + tid], x2 = kr[KVLR + 32 + tid];
        float r1 = x1 * cr[tid] - x2 * sr[tid];
        float r2 = x2 * cr[32 + tid] + x1 * sr[32 + tid];
        kc[512 + tid]      = (__bf16)r1;
        kc[512 + 32 + tid] = (__bf16)r2;
        kpe_s[tid]      = r1;
        kpe_s[32 + tid] = r2;
    }
    // rope q_pe in place in qb
    const int bb = (int)(row >> 10), sp = (int)(row & 1023);
    __bf16* qr = q + row * (NHD * QKD);
#pragma unroll
    for (int j = 0; j < 2; ++j) {
        int idx = tid + j * 256;
        int h = idx >> 5, p = idx & 31;
        __bf16* base = qr + h * QKD + NOPE;
        float x1 = (float)base[p], x2 = (float)base[32 + p];
        base[p]      = (__bf16)(x1 * cr[p] - x2 * sr[p]);
        base[32 + p] = (__bf16)(x2 * cr[32 + p] + x1 * sr[32 + p]);
    }
    __syncthreads();
    // broadcast k_pe into Khb for all 16 heads: 16*64 = 1024 values
#pragma unroll
    for (int j = 0; j < 4; ++j) {
        int idx = tid + j * 256;          // 0..1023
        int h = idx >> 6, c = idx & 63;
        Khb[((size_t)(bb * NHD + h) * SS + sp) * QKD + NOPE + c] = (__bf16)kpe_s[c];
    }
}

// ---------------------------------------------------------------------------
extern "C" void kernel_launch(void* const* d_in, const int* in_sizes, int n_in,
                              void* d_out, int out_size, void* d_ws, size_t ws_size,
                              hipStream_t stream)
{
    const float* hidden    = (const float*)d_in[0];
    const float* cosb      = (const float*)d_in[1];
    const float* sinb      = (const float*)d_in[2];
    const float* w_qa      = (const float*)d_in[3];
    const float* q_a_ln_w  = (const float*)d_in[4];
    const float* w_qb      = (const float*)d_in[5];
    const float* w_kva     = (const float*)d_in[6];
    const float* kv_a_ln_w = (const float*)d_in[7];
    const float* W_UK_T    = (const float*)d_in[8];
    const float* W_UV      = (const float*)d_in[9];
    const float* w_o       = (const float*)d_in[10];
    float* out = (float*)d_out;

    const int M = BB * SS;  // 2048
    // ---- R9-fix layout ----
    // HEAD scratch (dead before gemm_scores): qakva 17.8 + Xb 8 + qab 6.3
    //   = 32.1 MB, all under the 64 MiB Sc window.
    // Sc aliases d_ws[0, 64 MiB) — overlaps ONLY dead head scratch.
    // TAIL (persistent, starts at 64 MiB): qb first (survives Sc!).
    float*  qakva = (float*)d_ws;
    __bf16* Xb    = (__bf16*)(qakva + (size_t)M * NCOMB);
    __bf16* qab   = Xb    + (size_t)M * HH;
    __bf16* Sc    = (__bf16*)d_ws;                    // 32*SS*SS = 64 MiB
    __bf16* qb    = Sc    + (size_t)32 * SS * SS;     // M*3072 = 12.6MB (TAIL)
    __bf16* Kc    = qb    + (size_t)M * NHD * QKD;    // M*576
    __bf16* Khb   = Kc    + (size_t)M * 576;          // 32*1024*192 = 12.6MB
    __bf16* Vh    = Khb   + (size_t)32 * SS * QKD;    // 32*128*1024 = 8.4MB
    __bf16* ohb   = Vh    + (size_t)32 * VDIM * SS;   // M*2048
    __bf16* w_cmb = ohb   + (size_t)M * HH;           // 2176*2048
    __bf16* w_qbb = w_cmb + (size_t)NCOMB * HH;       // 3072*1536
    __bf16* Wkb   = w_qbb + (size_t)NHD * QKD * QLR;  // 16*128*512 (raw cast)
    __bf16* Wvb   = Wkb   + (size_t)NHD * NOPE * KVLR;// 16*128*512
    __bf16* w_ob  = Wvb   + (size_t)NHD * VDIM * KVLR;// 2048*2048

    dim3 blk(256);

    // --- casts ---
    castf2b<<<dim3((M * HH) / 1024), blk, 0, stream>>>(hidden, Xb, M * HH);
    cast_comb<<<dim3((NCOMB * HH) / 1024), blk, 0, stream>>>(w_qa, w_kva, w_cmb);
    castf2b<<<dim3((NHD * QKD * QLR) / 1024), blk, 0, stream>>>(w_qb, w_qbb, NHD * QKD * QLR);
    castf2b<<<dim3((HH * HH) / 1024), blk, 0, stream>>>(w_o, w_ob, HH * HH);
    // W_UK_T raw cast (no transpose needed for gemm_kh's B operand)
    castf2b<<<dim3((NHD * NOPE * KVLR) / 1024), blk, 0, stream>>>(W_UK_T, Wkb, NHD * NOPE * KVLR);
    transpose_cast<<<dim3(VDIM / 32, KVLR / 32, NHD), blk, 0, stream>>>(W_UV, Wvb, KVLR, VDIM);

    // 1+4 fused: qakva = Xb @ [w_qa; w_kva]^T   (2048 x 2176 x 2048)
    gemm_mfma<false, 64, 2, false><<<dim3(NCOMB / 128, M / 128, 1), blk, 0, stream>>>(
        Xb, w_cmb, qakva, M, NCOMB, HH, HH, HH, NCOMB, 0, 0, 0);
    // 2. qab = bf16(LN(qakva[:, :1536]))
    ln_kernel<<<dim3(M), blk, 0, stream>>>(qakva, q_a_ln_w, qab, QLR, NCOMB);
    // 3. qb = qab @ w_qb^T (bf16, tail-resident)  (2048 x 3072 x 1536)
    gemm_mfma<true, 64, 2, false><<<dim3(NHD * QKD / 128, M / 128, 1), blk, 0, stream>>>(
        qab, w_qbb, qb, M, NHD * QKD, QLR, QLR, QLR, NHD * QKD, 0, 0, 0);
    // 5. Kc = [LN(kv_c), rope(k_pe)]; rope q_pe in place; k_pe -> Khb cols
    prep_kernel<<<dim3(M), blk, 0, stream>>>(qakva + QLR, NCOMB, kv_a_ln_w,
                                             cosb, sinb, Kc, qb, Khb);
    // 5b. Vh[z] = Wvb[h] @ Kc[b][:, :512]^T   (32 x [128 x 1024 x 512])
    gemm_vh<<<dim3(8, 1, 32), blk, 0, stream>>>(Wvb, Kc, Vh);
    // 6. Khb[z][:, 0:128) = Kc[b] @ Wuk[h]^T  (32 x [1024 x 128 x 512])
    gemm_kh<<<dim3(8, 1, 32), blk, 0, stream>>>(Kc, Wkb, Khb);
    // 8a. Sc = causal scores, K=192, A = qb view (1152 blocks)
    gemm_scores<<<dim3(36, 32), blk, 0, stream>>>(qb, Khb, Sc);
    // 8b. row softmax in place
    softmax_kernel<<<dim3(SS / 4, 32), blk, 0, stream>>>(Sc);
    // 8c. ohb = P @ Vh^T (head-space PV, causal k-bound)
    gemm_pv<<<dim3(8, 32), blk, 0, stream>>>(Sc, Vh, ohb);
    // 10. out = ohb @ w_o^T (fp32)             (2048 x 2048 x 2048)
    gemm_mfma<false, 64, 2, false><<<dim3(HH / 128, M / 128, 1), blk, 0, stream>>>(
        ohb, w_ob, out, M, HH, NHD * VDIM, NHD * VDIM, NHD * VDIM, HH, 0, 0, 0);
}

// Round 11
// 285.037 us; speedup vs baseline: 1.0951x; 1.0483x over previous
//
#include <hip/hip_runtime.h>
#include <hip/hip_bf16.h>
#include <math.h>

#define BB 2
#define SS 1024
#define HH 2048
#define NHD 16
#define NOPE 128
#define ROPED 64
#define VDIM 128
#define QKD 192
#define QLR 1536
#define KVLR 512
#define EPSF 1e-5f
#define NCOMB 2176   // QLR + 576 kv + 64 pad

typedef __bf16 bf16x8 __attribute__((ext_vector_type(8)));
typedef float  f32x4  __attribute__((ext_vector_type(4)));

__device__ __forceinline__ void gload_lds16(const __bf16* g, __bf16* l) {
    __builtin_amdgcn_global_load_lds(
        (const __attribute__((address_space(1))) void*)g,
        (__attribute__((address_space(3))) void*)l, 16, 0, 0);
}

// XCD-chunked bijective tile swizzle (T1, validated R6: FETCH drop + ~8 µs).
__device__ __forceinline__ void swz2d(int nx, int ny, int& bx, int& by) {
    int T = nx * ny;
    int lin = blockIdx.x + nx * blockIdx.y;
    if ((T & 7) == 0) {
        int q = T >> 3;
        lin = (lin & 7) * q + (lin >> 3);
    }
    bx = lin % nx;
    by = lin / nx;
}

// ---------------------------------------------------------------------------
// Double-buffered 2-barrier core (R1 schedule, proven): for dense big-K GEMMs.
// XOR swizzle (both-sides involution, verified): BK=64 chunk^=row&7.
// ---------------------------------------------------------------------------
template<int BK>
__device__ __forceinline__ void gemm_core_dbuf(
    const __bf16* __restrict__ Ab, const __bf16* __restrict__ Bb,
    int lda, int ldb, int m0, int n0, int K, __bf16* lds, f32x4 acc[4][4])
{
    constexpr int CH    = BK / 8;
    constexpr int LPT   = CH / 2;
    constexpr int BUFE  = 256 * BK;
    constexpr int BOFF  = 128 * BK;
    constexpr int RSTEP = 2048 / BK;
    const int tid = threadIdx.x;
    const int w = tid >> 6, lane = tid & 63, quad = lane >> 4, ln = lane & 15;
    const int wm = (w >> 1) * 64, wn = (w & 1) * 64;
    const int nt = K / BK;

    const int sr  = tid / CH;
    const int spc = tid % CH;
    const int sc  = (BK == 64) ? (spc ^ (sr & 7)) : (spc ^ ((sr >> 1) & 3));
    const __bf16* gA = Ab + (size_t)(m0 + sr) * lda + sc * 8;
    const __bf16* gB = Bb + (size_t)(n0 + sr) * ldb + sc * 8;

    const int swm = (BK == 64) ? ((wm + ln) & 7) : (((wm + ln) >> 1) & 3);
    const int swn = (BK == 64) ? ((wn + ln) & 7) : (((wn + ln) >> 1) & 3);

    auto stage = [&](int buf, int kk) {
        __bf16* la = lds + buf * BUFE + w * 512;
        __bf16* lb = la + BOFF;
        const __bf16* ga = gA + kk;
        const __bf16* gb = gB + kk;
#pragma unroll
        for (int i = 0; i < LPT; ++i) {
            gload_lds16(ga + (size_t)(i * RSTEP) * lda, la + i * 2048);
            gload_lds16(gb + (size_t)(i * RSTEP) * ldb, lb + i * 2048);
        }
    };
    auto wait_stage = [&]() {
        if constexpr (BK == 64) asm volatile("s_waitcnt vmcnt(8)" ::: "memory");
        else                    asm volatile("s_waitcnt vmcnt(4)" ::: "memory");
    };

    stage(0, 0);
    stage(1, BK);
    wait_stage();
    __builtin_amdgcn_s_barrier();
    __builtin_amdgcn_sched_barrier(0);

    for (int t = 0; t < nt; ++t) {
        const int cur = t & 1;
        const __bf16* bufA = lds + cur * BUFE;
        const __bf16* bufB = bufA + BOFF;
        bf16x8 af[BK / 32][4], bv[BK / 32][4];
#pragma unroll
        for (int ks = 0; ks < BK / 32; ++ks)
#pragma unroll
            for (int i = 0; i < 4; ++i) {
                af[ks][i] = *(const bf16x8*)
                    &bufA[(wm + ln) * BK + i * 16 * BK + (((ks * 4 + quad) ^ swm) << 3)];
                bv[ks][i] = *(const bf16x8*)
                    &bufB[(wn + ln) * BK + i * 16 * BK + (((ks * 4 + quad) ^ swn) << 3)];
            }
        __builtin_amdgcn_s_setprio(1);
#pragma unroll
        for (int ks = 0; ks < BK / 32; ++ks)
#pragma unroll
            for (int mi = 0; mi < 4; ++mi)
#pragma unroll
                for (int ni = 0; ni < 4; ++ni)
                    acc[mi][ni] = __builtin_amdgcn_mfma_f32_16x16x32_bf16(
                        af[ks][mi], bv[ks][ni], acc[mi][ni], 0, 0, 0);
        __builtin_amdgcn_s_setprio(0);
        if (t + 1 < nt) {
            __builtin_amdgcn_sched_barrier(0);
            asm volatile("" ::: "memory");
            __builtin_amdgcn_s_barrier();          // (a) reads of buf[cur] done
            asm volatile("" ::: "memory");
            if (t + 2 < nt) {
                stage(cur, (t + 2) * BK);
                wait_stage();
            } else {
                asm volatile("s_waitcnt vmcnt(0)" ::: "memory");
            }
            __builtin_amdgcn_s_barrier();          // (b) publish t+1
            __builtin_amdgcn_sched_barrier(0);
        }
    }
}

// ---------------------------------------------------------------------------
// Triple-buffered 1-barrier core (BK=32: 48 KB LDS -> 3 blocks/CU).
// Proven R4; R8 compiler-scheduled ds_read->MFMA (neutral, kept).
// ---------------------------------------------------------------------------
template<int BK>
__device__ __forceinline__ void gemm_core_tri(
    const __bf16* __restrict__ Ab, const __bf16* __restrict__ Bb,
    int lda, int ldb, int m0, int n0, int K, __bf16* lds, f32x4 acc[4][4])
{
    constexpr int CH    = BK / 8;
    constexpr int LPT   = CH / 2;
    constexpr int BUFE  = 256 * BK;
    constexpr int BOFF  = 128 * BK;
    constexpr int RSTEP = 2048 / BK;
    const int tid = threadIdx.x;
    const int w = tid >> 6, lane = tid & 63, quad = lane >> 4, ln = lane & 15;
    const int wm = (w >> 1) * 64, wn = (w & 1) * 64;
    const int nt = K / BK;

    const int sr  = tid / CH;
    const int spc = tid % CH;
    const int sc  = (BK == 64) ? (spc ^ (sr & 7)) : (spc ^ ((sr >> 1) & 3));
    const __bf16* gA = Ab + (size_t)(m0 + sr) * lda + sc * 8;
    const __bf16* gB = Bb + (size_t)(n0 + sr) * ldb + sc * 8;

    const int swm = (BK == 64) ? ((wm + ln) & 7) : (((wm + ln) >> 1) & 3);
    const int swn = (BK == 64) ? ((wn + ln) & 7) : (((wn + ln) >> 1) & 3);

    auto stage = [&](__bf16* base, int kk) {
        __bf16* la = base + w * 512;
        __bf16* lb = la + BOFF;
        const __bf16* ga = gA + kk;
        const __bf16* gb = gB + kk;
#pragma unroll
        for (int i = 0; i < LPT; ++i) {
            gload_lds16(ga + (size_t)(i * RSTEP) * lda, la + i * 2048);
            gload_lds16(gb + (size_t)(i * RSTEP) * ldb, lb + i * 2048);
        }
    };

    __bf16* p0 = lds;               // tile t
    __bf16* p1 = lds + BUFE;        // tile t+1
    __bf16* p2 = lds + 2 * BUFE;    // stage target (tile t+2)

    stage(p0, 0);
    stage(p1, BK);
    if constexpr (BK == 64) asm volatile("s_waitcnt vmcnt(8)" ::: "memory");
    else                    asm volatile("s_waitcnt vmcnt(4)" ::: "memory");
    __builtin_amdgcn_s_barrier();
    __builtin_amdgcn_sched_barrier(0);

    for (int t = 0; t < nt; ++t) {
        if (t + 2 < nt) stage(p2, (t + 2) * BK);   // issue global loads first
        bf16x8 af[BK / 32][4], bv[BK / 32][4];
#pragma unroll
        for (int ks = 0; ks < BK / 32; ++ks)
#pragma unroll
            for (int i = 0; i < 4; ++i) {
                af[ks][i] = *(const bf16x8*)
                    &p0[(wm + ln) * BK + i * 16 * BK + (((ks * 4 + quad) ^ swm) << 3)];
                bv[ks][i] = *(const bf16x8*)
                    &p0[BOFF + (wn + ln) * BK + i * 16 * BK + (((ks * 4 + quad) ^ swn) << 3)];
            }
        __builtin_amdgcn_s_setprio(1);
#pragma unroll
        for (int ks = 0; ks < BK / 32; ++ks)
#pragma unroll
            for (int mi = 0; mi < 4; ++mi)
#pragma unroll
                for (int ni = 0; ni < 4; ++ni)
                    acc[mi][ni] = __builtin_amdgcn_mfma_f32_16x16x32_bf16(
                        af[ks][mi], bv[ks][ni], acc[mi][ni], 0, 0, 0);
        __builtin_amdgcn_s_setprio(0);
        if (t + 1 < nt) {
            __builtin_amdgcn_sched_barrier(0);
            if (t + 2 < nt) {
                if constexpr (BK == 64) asm volatile("s_waitcnt vmcnt(8)" ::: "memory");
                else                    asm volatile("s_waitcnt vmcnt(4)" ::: "memory");
            } else {
                asm volatile("s_waitcnt vmcnt(0)" ::: "memory");
            }
            __builtin_amdgcn_s_barrier();          // single barrier per tile
            __builtin_amdgcn_sched_barrier(0);
        }
        __bf16* tmp = p0; p0 = p1; p1 = p2; p2 = tmp;
    }
}

// ---------------------------------------------------------------------------
// MFMA bf16 GEMM: C[M,N] = A[M,K] @ B[N,K]^T (batched via blockIdx.z),
// with XCD-chunked tile swizzle.
// ---------------------------------------------------------------------------
template<bool OUT_BF16, int BK, int MINW, bool TRI>
__global__ __launch_bounds__(256, MINW) void gemm_mfma(
    const __bf16* __restrict__ A, const __bf16* __restrict__ B, void* __restrict__ Cv,
    int M, int N, int K, int lda, int ldb, int ldc,
    long long sA, long long sB, long long sC)
{
    __shared__ __bf16 lds[TRI ? 768 * BK : 512 * BK];
    const __bf16* Ab = A + (long long)blockIdx.z * sA;
    const __bf16* Bb = B + (long long)blockIdx.z * sB;
    const int tid = threadIdx.x;
    const int w = tid >> 6, lane = tid & 63, quad = lane >> 4, ln = lane & 15;
    int bx, by; swz2d(gridDim.x, gridDim.y, bx, by);
    const int m0 = by * 128, n0 = bx * 128;
    const int wm = (w >> 1) * 64, wn = (w & 1) * 64;

    f32x4 acc[4][4];
#pragma unroll
    for (int i = 0; i < 4; ++i)
#pragma unroll
        for (int j = 0; j < 4; ++j) acc[i][j] = (f32x4){0.f, 0.f, 0.f, 0.f};

    if (TRI) gemm_core_tri<BK>(Ab, Bb, lda, ldb, m0, n0, K, lds, acc);
    else     gemm_core_dbuf<BK>(Ab, Bb, lda, ldb, m0, n0, K, lds, acc);

    if (OUT_BF16) {
        __bf16* Cb = (__bf16*)Cv + (long long)blockIdx.z * sC;
#pragma unroll
        for (int mi = 0; mi < 4; ++mi)
#pragma unroll
            for (int r = 0; r < 4; ++r) {
                size_t row = (size_t)(m0 + wm + mi * 16 + quad * 4 + r);
#pragma unroll
                for (int ni = 0; ni < 4; ++ni)
                    Cb[row * ldc + (n0 + wn + ni * 16 + ln)] = (__bf16)acc[mi][ni][r];
            }
    } else {
        float* Cb = (float*)Cv + (long long)blockIdx.z * sC;
#pragma unroll
        for (int mi = 0; mi < 4; ++mi)
#pragma unroll
            for (int r = 0; r < 4; ++r) {
                size_t row = (size_t)(m0 + wm + mi * 16 + quad * 4 + r);
#pragma unroll
                for (int ni = 0; ni < 4; ++ni)
                    Cb[row * ldc + (n0 + wn + ni * 16 + ln)] = acc[mi][ni][r];
            }
    }
}

// ---------------------------------------------------------------------------
// Fused Vh + Kh kernel (R11): 512 blocks (2/CU — vh and kh blocks co-resident
// cover each other's stalls; was 2 x 256-block launches at 1/CU).
//   sub<8:  Vh[z][128v][1024s] = Wvb[h] @ Kc[b][:, :512]^T   (ntile = sub)
//   sub>=8: Khb[z][s][0..128)  = Kc[b][:, :512] @ Wuk[h]^T   (mt = sub-8)
// Chunk swizzle keeps 4 consecutive z per XCD (Kc[b] L2-local).
// ---------------------------------------------------------------------------
__global__ __launch_bounds__(256, 3) void gemm_vhkh(
    const __bf16* __restrict__ Wvb, const __bf16* __restrict__ Wuk,
    const __bf16* __restrict__ Kc, __bf16* __restrict__ Vh,
    __bf16* __restrict__ Khb)
{
    int lin = blockIdx.x + 16 * blockIdx.z;          // grid (16,1,32) -> 0..511
    lin = (lin & 7) * 64 + (lin >> 3);               // bijective chunk swizzle
    const int z = lin >> 4;
    const int sub = lin & 15;
    const int b = z >> 4, h = z & 15;

    __shared__ __bf16 lds[768 * 32];
    const int tid = threadIdx.x;
    const int w = tid >> 6, lane = tid & 63, quad = lane >> 4, ln = lane & 15;
    const int wm = (w >> 1) * 64, wn = (w & 1) * 64;

    f32x4 acc[4][4];
#pragma unroll
    for (int i = 0; i < 4; ++i)
#pragma unroll
        for (int j = 0; j < 4; ++j) acc[i][j] = (f32x4){0.f, 0.f, 0.f, 0.f};

    if (sub < 8) {
        const __bf16* Ab = Wvb + (size_t)h * VDIM * KVLR;
        const __bf16* Bb = Kc + (size_t)b * SS * 576;
        const int m0 = 0, n0 = sub * 128;
        gemm_core_tri<32>(Ab, Bb, KVLR, 576, m0, n0, KVLR, lds, acc);
        __bf16* Cb = Vh + (size_t)z * VDIM * SS;     // [128][1024]
#pragma unroll
        for (int mi = 0; mi < 4; ++mi)
#pragma unroll
            for (int r = 0; r < 4; ++r) {
                int row = m0 + wm + mi * 16 + quad * 4 + r;
#pragma unroll
                for (int ni = 0; ni < 4; ++ni)
                    Cb[(size_t)row * SS + (n0 + wn + ni * 16 + ln)] = (__bf16)acc[mi][ni][r];
            }
    } else {
        const __bf16* Ab = Kc + (size_t)b * SS * 576;
        const __bf16* Bb = Wuk + (size_t)h * NOPE * KVLR;
        const int m0 = (sub - 8) * 128, n0 = 0;
        gemm_core_tri<32>(Ab, Bb, 576, KVLR, m0, n0, KVLR, lds, acc);
        __bf16* Cb = Khb + (size_t)z * SS * QKD;     // [1024][192]
#pragma unroll
        for (int mi = 0; mi < 4; ++mi)
#pragma unroll
            for (int r = 0; r < 4; ++r) {
                int row = m0 + wm + mi * 16 + quad * 4 + r;
#pragma unroll
                for (int ni = 0; ni < 4; ++ni)
                    Cb[(size_t)row * QKD + (n0 + wn + ni * 16 + ln)] = (__bf16)acc[mi][ni][r];
            }
    }
}

// ---------------------------------------------------------------------------
// Causal scores GEMM (R9): Sc[z] = (q[h] @ Khb[z]^T) * scale, K=192. A is a
// strided VIEW of qb (row stride 3072, head offset h*192). qb is TAIL-
// resident (survives Sc writes — Sc aliases only dead head scratch).
// ---------------------------------------------------------------------------
__global__ __launch_bounds__(256, 3) void gemm_scores(
    const __bf16* __restrict__ qb, const __bf16* __restrict__ Khb,
    __bf16* __restrict__ Sc)
{
    int lin = blockIdx.x + 36 * blockIdx.y;          // 0..1151
    lin = (lin & 7) * 144 + (lin >> 3);              // bijective chunk swizzle
    const int z = lin / 36;
    const int i = lin - z * 36;
    int mt = (int)((sqrtf(8.f * i + 1.f) - 1.f) * 0.5f);
    if (mt * (mt + 1) / 2 > i) --mt;
    if ((mt + 1) * (mt + 2) / 2 <= i) ++mt;
    const int nt = i - mt * (mt + 1) / 2;

    const int b = z >> 4, h = z & 15;
    __shared__ __bf16 lds[768 * 32];
    const __bf16* Ab = qb + (size_t)b * SS * (NHD * QKD) + (size_t)h * QKD;
    const __bf16* Bb = Khb + (size_t)z * SS * QKD;
    __bf16* Cb = Sc + (size_t)z * SS * SS;
    const int tid = threadIdx.x;
    const int w = tid >> 6, lane = tid & 63, quad = lane >> 4, ln = lane & 15;
    const int m0 = mt * 128, n0 = nt * 128;
    const int wm = (w >> 1) * 64, wn = (w & 1) * 64;

    f32x4 acc[4][4];
#pragma unroll
    for (int i2 = 0; i2 < 4; ++i2)
#pragma unroll
        for (int j = 0; j < 4; ++j) acc[i2][j] = (f32x4){0.f, 0.f, 0.f, 0.f};

    gemm_core_tri<32>(Ab, Bb, NHD * QKD, QKD, m0, n0, QKD, lds, acc);

    const float SCL2 = 0.07216878364870323f * 1.4426950408889634f;  // scale*log2e
#pragma unroll
    for (int mi = 0; mi < 4; ++mi)
#pragma unroll
        for (int r = 0; r < 4; ++r) {
            int row = m0 + wm + mi * 16 + quad * 4 + r;
#pragma unroll
            for (int ni = 0; ni < 4; ++ni) {
                int col = n0 + wn + ni * 16 + ln;
                float v = acc[mi][ni][r] * SCL2;
                if (col > row) v = -1e30f;
                Cb[(size_t)row * SS + col] = (__bf16)v;
            }
        }
}

// ---------------------------------------------------------------------------
// Row softmax (exp2 domain). One wave per row, shfl-only reductions.
// ---------------------------------------------------------------------------
__global__ __launch_bounds__(256) void softmax_kernel(__bf16* __restrict__ Sc)
{
    const int z = blockIdx.y;
    const int w = threadIdx.x >> 6, lane = threadIdx.x & 63;
    const int r = blockIdx.x * 4 + w;
    __bf16* row = Sc + (size_t)z * SS * SS + (size_t)r * SS;
    const int ncols = ((r >> 7) + 1) << 7;
    const int i0 = lane * 8, i1 = i0 + 512;
    const bool a0 = i0 < ncols, a1 = i1 < ncols;
    float v[16];
    float lmax = -1e30f;
    if (a0) {
        bf16x8 c = *(const bf16x8*)(row + i0);
#pragma unroll
        for (int j = 0; j < 8; ++j) { v[j] = (float)c[j]; lmax = fmaxf(lmax, v[j]); }
    }
    if (a1) {
        bf16x8 c = *(const bf16x8*)(row + i1);
#pragma unroll
        for (int j = 0; j < 8; ++j) { v[8 + j] = (float)c[j]; lmax = fmaxf(lmax, v[8 + j]); }
    }
#pragma unroll
    for (int off = 1; off < 64; off <<= 1) lmax = fmaxf(lmax, __shfl_xor(lmax, off));
    float lsum = 0.f;
    if (a0) {
#pragma unroll
        for (int j = 0; j < 8; ++j) { v[j] = __builtin_amdgcn_exp2f(v[j] - lmax); lsum += v[j]; }
    }
    if (a1) {
#pragma unroll
        for (int j = 0; j < 8; ++j) { v[8 + j] = __builtin_amdgcn_exp2f(v[8 + j] - lmax); lsum += v[8 + j]; }
    }
#pragma unroll
    for (int off = 1; off < 64; off <<= 1) lsum += __shfl_xor(lsum, off);
    const float inv = 1.f / lsum;
    if (a0) {
        bf16x8 c;
#pragma unroll
        for (int j = 0; j < 8; ++j) c[j] = (__bf16)(v[j] * inv);
        *(bf16x8*)(row + i0) = c;
    }
    if (a1) {
        bf16x8 c;
#pragma unroll
        for (int j = 0; j < 8; ++j) c[j] = (__bf16)(v[8 + j] * inv);
        *(bf16x8*)(row + i1) = c;
    }
}

// ---------------------------------------------------------------------------
// PV GEMM (R7, head-space): ohb[b, s, h*128+v] = P[z] @ Vh[z]^T.
// ---------------------------------------------------------------------------
__global__ __launch_bounds__(256, 3) void gemm_pv(
    const __bf16* __restrict__ Sc, const __bf16* __restrict__ Vh,
    __bf16* __restrict__ ohb)
{
    int lin = blockIdx.x + 8 * blockIdx.y;           // 0..255
    lin = (lin & 7) * 32 + (lin >> 3);               // bijective chunk swizzle
    const int z = lin >> 3;
    const int mt = lin & 7;

    const int b = z >> 4, h = z & 15;
    const int Keff = (mt + 1) * 128;
    __shared__ __bf16 lds[768 * 32];
    const __bf16* Ab = Sc + (size_t)z * SS * SS;
    const __bf16* Bb = Vh + (size_t)z * VDIM * SS;
    const int tid = threadIdx.x;
    const int w = tid >> 6, lane = tid & 63, quad = lane >> 4, ln = lane & 15;
    const int m0 = mt * 128, n0 = 0;
    const int wm = (w >> 1) * 64, wn = (w & 1) * 64;

    f32x4 acc[4][4];
#pragma unroll
    for (int i = 0; i < 4; ++i)
#pragma unroll
        for (int j = 0; j < 4; ++j) acc[i][j] = (f32x4){0.f, 0.f, 0.f, 0.f};

    gemm_core_tri<32>(Ab, Bb, SS, SS, m0, n0, Keff, lds, acc);

#pragma unroll
    for (int mi = 0; mi < 4; ++mi)
#pragma unroll
        for (int r = 0; r < 4; ++r) {
            int row = m0 + wm + mi * 16 + quad * 4 + r;
            __bf16* op = ohb + (size_t)(b * SS + row) * (NHD * VDIM) + h * VDIM;
#pragma unroll
            for (int ni = 0; ni < 4; ++ni)
                op[n0 + wn + ni * 16 + ln] = (__bf16)acc[mi][ni][r];
        }
}

// ---------------------------------------------------------------------------
// Fused cast kernel (R11): one launch for hidden + all non-transposed
// weight casts. Region boundaries are multiples of 4 (no intra-quad split).
// ---------------------------------------------------------------------------
#define N_XB   (2048LL * 2048)
#define N_CMB  ((long long)NCOMB * HH)
#define N_QBB  (3072LL * 1536)
#define N_WKB  ((long long)NHD * NOPE * KVLR)
#define N_WOB  ((long long)HH * HH)
#define TB1 (N_XB)
#define TB2 (TB1 + N_CMB)
#define TB3 (TB2 + N_QBB)
#define TB4 (TB3 + N_WKB)
#define TB5 (TB4 + N_WOB)   // 18,612,224 total

__global__ __launch_bounds__(256) void cast_weights(
    const float* __restrict__ hidden, const float* __restrict__ wqa,
    const float* __restrict__ wkva, const float* __restrict__ wqb,
    const float* __restrict__ wuk, const float* __restrict__ wo,
    __bf16* __restrict__ Xb, __bf16* __restrict__ w_cmb,
    __bf16* __restrict__ w_qbb, __bf16* __restrict__ Wkb,
    __bf16* __restrict__ w_ob)
{
    long long idx = ((long long)blockIdx.x * 256 + threadIdx.x) * 4;
    if (idx >= TB5) return;
    const float* src;
    __bf16* dst;
    if (idx < TB1) { src = hidden + idx; dst = Xb + idx; }
    else if (idx < TB2) {
        long long l = idx - TB1;
        int row = (int)(l >> 11), col = (int)(l & 2047);
        dst = w_cmb + l;
        if (row < 1536)      src = wqa + (size_t)row * 2048 + col;
        else if (row < 2112) src = wkva + (size_t)(row - 1536) * 2048 + col;
        else {
            dst[0] = (__bf16)0.f; dst[1] = (__bf16)0.f;
            dst[2] = (__bf16)0.f; dst[3] = (__bf16)0.f;
            return;
        }
    }
    else if (idx < TB3) { long long l = idx - TB2; src = wqb + l; dst = w_qbb + l; }
    else if (idx < TB4) { long long l = idx - TB3; src = wuk + l; dst = Wkb + l; }
    else                { long long l = idx - TB4; src = wo + l;  dst = w_ob + l; }
    float4 v = *(const float4*)src;
    dst[0] = (__bf16)v.x; dst[1] = (__bf16)v.y;
    dst[2] = (__bf16)v.z; dst[3] = (__bf16)v.w;
}

// batched transpose-cast: in[z][R][C] fp32 -> out[z][C][R] bf16
__global__ __launch_bounds__(256) void transpose_cast(const float* __restrict__ in,
                                                      __bf16* __restrict__ out,
                                                      int R, int C)
{
    __shared__ float t[32][33];
    in  += (size_t)blockIdx.z * R * C;
    out += (size_t)blockIdx.z * R * C;
    int c0 = blockIdx.x * 32, r0 = blockIdx.y * 32;
    int tx = threadIdx.x & 31, ty = threadIdx.x >> 5;
#pragma unroll
    for (int i = 0; i < 4; ++i) {
        int r = ty + i * 8;
        t[r][tx] = in[(size_t)(r0 + r) * C + c0 + tx];
    }
    __syncthreads();
#pragma unroll
    for (int i = 0; i < 4; ++i) {
        int rr = ty + i * 8;
        out[(size_t)(c0 + rr) * R + r0 + tx] = (__bf16)t[tx][rr];
    }
}

// ---------------------------------------------------------------------------
// LayerNorm fp32 in (row stride ldx) -> bf16 out (row stride N).
// ---------------------------------------------------------------------------
__global__ __launch_bounds__(256) void ln_kernel(const float* __restrict__ x,
                                                 const float* __restrict__ w,
                                                 __bf16* __restrict__ y, int N, int ldx)
{
    long long row = blockIdx.x;
    const float* xr = x + row * ldx;
    __bf16* yr = y + row * N;
    int tid = threadIdx.x;
    float s = 0.f, ss = 0.f;
    for (int i = tid; i < N; i += 256) { float v = xr[i]; s += v; ss += v * v; }
#pragma unroll
    for (int off = 32; off > 0; off >>= 1) { s += __shfl_down(s, off); ss += __shfl_down(ss, off); }
    __shared__ float rs[4], rss[4];
    __shared__ float smean, sinv;
    int wave = tid >> 6, lane = tid & 63;
    if (lane == 0) { rs[wave] = s; rss[wave] = ss; }
    __syncthreads();
    if (tid == 0) {
        float S = rs[0] + rs[1] + rs[2] + rs[3];
        float Q = rss[0] + rss[1] + rss[2] + rss[3];
        float mean = S / N;
        float var = Q / N - mean * mean;
        smean = mean; sinv = rsqrtf(var + EPSF);
    }
    __syncthreads();
    float mean = smean, inv = sinv;
    for (int i = tid; i < N; i += 256) yr[i] = (__bf16)((xr[i] - mean) * inv * w[i]);
}

// ---------------------------------------------------------------------------
// Per-token prep (R9): Kc[row] = bf16(concat(LN(kva[:512])*w, rope(k_pe)));
// ropes q_pe IN PLACE in qb; broadcasts roped k_pe into Khb[z][sp][128..192)
// for all 16 heads (cols 0..127 of Khb are written by gemm_vhkh — disjoint).
// ---------------------------------------------------------------------------
__global__ __launch_bounds__(256) void prep_kernel(
    const float* __restrict__ kva, int ld, const float* __restrict__ kvw,
    const float* __restrict__ cosb, const float* __restrict__ sinb,
    __bf16* __restrict__ Kc, __bf16* __restrict__ q,
    __bf16* __restrict__ Khb)
{
    long long row = blockIdx.x;
    const float* kr = kva + row * ld;
    const float* cr = cosb + row * ROPED;
    const float* sr = sinb + row * ROPED;
    int tid = threadIdx.x;
    float v0 = kr[tid], v1 = kr[tid + 256];
    float s = v0 + v1, ss = v0 * v0 + v1 * v1;
#pragma unroll
    for (int off = 32; off > 0; off >>= 1) { s += __shfl_down(s, off); ss += __shfl_down(ss, off); }
    __shared__ float rs[4], rss[4];
    __shared__ float smean, sinv;
    __shared__ float kpe_s[64];
    int wave = tid >> 6, lane = tid & 63;
    if (lane == 0) { rs[wave] = s; rss[wave] = ss; }
    __syncthreads();
    if (tid == 0) {
        float S = rs[0] + rs[1] + rs[2] + rs[3];
        float Q = rss[0] + rss[1] + rss[2] + rss[3];
        float mean = S / KVLR;
        float var = Q / KVLR - mean * mean;
        smean = mean; sinv = rsqrtf(var + EPSF);
    }
    __syncthreads();
    float mean = smean, inv = sinv;
    __bf16* kc = Kc + row * 576;
    kc[tid]       = (__bf16)((v0 - mean) * inv * kvw[tid]);
    kc[tid + 256] = (__bf16)((v1 - mean) * inv * kvw[tid + 256]);
    if (tid < 32) {
        float x1 = kr[KVLR + tid], x2 = kr[KVLR + 32 + tid];
        float r1 = x1 * cr[tid] - x2 * sr[tid];
        float r2 = x2 * cr[32 + tid] + x1 * sr[32 + tid];
        kc[512 + tid]      = (__bf16)r1;
        kc[512 + 32 + tid] = (__bf16)r2;
        kpe_s[tid]      = r1;
        kpe_s[32 + tid] = r2;
    }
    // rope q_pe in place in qb
    const int bb = (int)(row >> 10), sp = (int)(row & 1023);
    __bf16* qr = q + row * (NHD * QKD);
#pragma unroll
    for (int j = 0; j < 2; ++j) {
        int idx = tid + j * 256;
        int h = idx >> 5, p = idx & 31;
        __bf16* base = qr + h * QKD + NOPE;
        float x1 = (float)base[p], x2 = (float)base[32 + p];
        base[p]      = (__bf16)(x1 * cr[p] - x2 * sr[p]);
        base[32 + p] = (__bf16)(x2 * cr[32 + p] + x1 * sr[32 + p]);
    }
    __syncthreads();
    // broadcast k_pe into Khb for all 16 heads: 16*64 = 1024 values
#pragma unroll
    for (int j = 0; j < 4; ++j) {
        int idx = tid + j * 256;          // 0..1023
        int h = idx >> 6, c = idx & 63;
        Khb[((size_t)(bb * NHD + h) * SS + sp) * QKD + NOPE + c] = (__bf16)kpe_s[c];
    }
}

// ---------------------------------------------------------------------------
extern "C" void kernel_launch(void* const* d_in, const int* in_sizes, int n_in,
                              void* d_out, int out_size, void* d_ws, size_t ws_size,
                              hipStream_t stream)
{
    const float* hidden    = (const float*)d_in[0];
    const float* cosb      = (const float*)d_in[1];
    const float* sinb      = (const float*)d_in[2];
    const float* w_qa      = (const float*)d_in[3];
    const float* q_a_ln_w  = (const float*)d_in[4];
    const float* w_qb      = (const float*)d_in[5];
    const float* w_kva     = (const float*)d_in[6];
    const float* kv_a_ln_w = (const float*)d_in[7];
    const float* W_UK_T    = (const float*)d_in[8];
    const float* W_UV      = (const float*)d_in[9];
    const float* w_o       = (const float*)d_in[10];
    float* out = (float*)d_out;

    const int M = BB * SS;  // 2048
    // ---- Layout (R10-proven) ----
    // HEAD scratch (dead before gemm_scores): qakva 17.8 + Xb 8 + qab 6.3 MB
    // under the 64 MiB Sc window. TAIL persists from 64 MiB: qb first.
    float*  qakva = (float*)d_ws;
    __bf16* Xb    = (__bf16*)(qakva + (size_t)M * NCOMB);
    __bf16* qab   = Xb    + (size_t)M * HH;
    __bf16* Sc    = (__bf16*)d_ws;                    // 32*SS*SS = 64 MiB
    __bf16* qb    = Sc    + (size_t)32 * SS * SS;     // M*3072 (TAIL)
    __bf16* Kc    = qb    + (size_t)M * NHD * QKD;    // M*576
    __bf16* Khb   = Kc    + (size_t)M * 576;          // 32*1024*192
    __bf16* Vh    = Khb   + (size_t)32 * SS * QKD;    // 32*128*1024
    __bf16* ohb   = Vh    + (size_t)32 * VDIM * SS;   // M*2048
    __bf16* w_cmb = ohb   + (size_t)M * HH;           // 2176*2048
    __bf16* w_qbb = w_cmb + (size_t)NCOMB * HH;       // 3072*1536
    __bf16* Wkb   = w_qbb + (size_t)NHD * QKD * QLR;  // 16*128*512 (raw cast)
    __bf16* Wvb   = Wkb   + (size_t)NHD * NOPE * KVLR;// 16*128*512
    __bf16* w_ob  = Wvb   + (size_t)NHD * VDIM * KVLR;// 2048*2048

    dim3 blk(256);

    // --- fused casts (1 launch) + W_UV transpose ---
    cast_weights<<<dim3((unsigned)(TB5 / 1024)), blk, 0, stream>>>(
        hidden, w_qa, w_kva, w_qb, W_UK_T, w_o,
        Xb, w_cmb, w_qbb, Wkb, w_ob);
    transpose_cast<<<dim3(VDIM / 32, KVLR / 32, NHD), blk, 0, stream>>>(W_UV, Wvb, KVLR, VDIM);

    // 1+4 fused: qakva = Xb @ [w_qa; w_kva]^T   (2048 x 2176 x 2048)
    gemm_mfma<false, 64, 2, false><<<dim3(NCOMB / 128, M / 128, 1), blk, 0, stream>>>(
        Xb, w_cmb, qakva, M, NCOMB, HH, HH, HH, NCOMB, 0, 0, 0);
    // 2. qab = bf16(LN(qakva[:, :1536]))
    ln_kernel<<<dim3(M), blk, 0, stream>>>(qakva, q_a_ln_w, qab, QLR, NCOMB);
    // 3. qb = qab @ w_qb^T (bf16, tail-resident)  (2048 x 3072 x 1536)
    gemm_mfma<true, 64, 2, false><<<dim3(NHD * QKD / 128, M / 128, 1), blk, 0, stream>>>(
        qab, w_qbb, qb, M, NHD * QKD, QLR, QLR, QLR, NHD * QKD, 0, 0, 0);
    // 5. Kc = [LN(kv_c), rope(k_pe)]; rope q_pe in place; k_pe -> Khb cols
    prep_kernel<<<dim3(M), blk, 0, stream>>>(qakva + QLR, NCOMB, kv_a_ln_w,
                                             cosb, sinb, Kc, qb, Khb);
    // 5b+6 fused: Vh and Khb[:, 0:128) in one 512-block launch
    gemm_vhkh<<<dim3(16, 1, 32), blk, 0, stream>>>(Wvb, Wkb, Kc, Vh, Khb);
    // 8a. Sc = causal scores, K=192, A = qb view (1152 blocks)
    gemm_scores<<<dim3(36, 32), blk, 0, stream>>>(qb, Khb, Sc);
    // 8b. row softmax in place
    softmax_kernel<<<dim3(SS / 4, 32), blk, 0, stream>>>(Sc);
    // 8c. ohb = P @ Vh^T (head-space PV, causal k-bound)
    gemm_pv<<<dim3(8, 32), blk, 0, stream>>>(Sc, Vh, ohb);
    // 10. out = ohb @ w_o^T (fp32)             (2048 x 2048 x 2048)
    gemm_mfma<false, 64, 2, false><<<dim3(HH / 128, M / 128, 1), blk, 0, stream>>>(
        ohb, w_ob, out, M, HH, NHD * VDIM, NHD * VDIM, NHD * VDIM, HH, 0, 0, 0);
}